// Round 1
// 711.367 us; speedup vs baseline: 1.0070x; 1.0070x over previous
//
#include <hip/hip_runtime.h>
#include <hip/hip_bf16.h>
#include <hip/hip_fp16.h>

#define N_NODES 100000
#define N_EDGES 1600000
#define HID     64
#define LAYERS  8
#define OUT_DIM 40
#define SCAN_NB 98   // ceil(100000/1024)
#define T0SL4   ((size_t)(N_NODES + 32) * 16)   // elements per t0 quarter-slice (16 feats)
#define NBUK    196      // ceil(100000/512) buckets of 512 nodes
#define BUK_CAP 12000    // avg 8163/bucket -> huge sigma headroom
#define S1_EPB  2048     // edges per bucket1 block (256 thr x 8)
#define AGG_N   128      // nodes per agg block
#define AGG_CAP 3072     // staged csr entries (mean 2048, +22 sigma), 12KB LDS

typedef __attribute__((ext_vector_type(8))) short short8;
typedef __attribute__((ext_vector_type(8))) _Float16 half8;
typedef __attribute__((ext_vector_type(4))) float float4v;

// ---------- runtime environment hedges ----------
// flags[0] = 1 if feature inputs are float32 (else bf16)
// flags[1] = 1 if edge_index is int64 (else int32)
__device__ inline float ldext(const void* p, bool f32, size_t i) {
    return f32 ? ((const float*)p)[i]
               : __bfloat162float(((const __hip_bfloat16*)p)[i]);
}
__device__ inline int load_edge(const void* raw, bool is64, long long idx) {
    return is64 ? (int)((const long long*)raw)[idx] : ((const int*)raw)[idx];
}
__device__ inline unsigned pack_bf16x2(float lo, float hi) {
    union { __hip_bfloat16 b; unsigned short u; } a, b;
    a.b = __float2bfloat16(lo);
    b.b = __float2bfloat16(hi);
    return ((unsigned)b.u << 16) | a.u;
}
__device__ inline unsigned short bf16bits(float v) {
    union { __hip_bfloat16 b; unsigned short u; } a;
    a.b = __float2bfloat16(v);
    return a.u;
}
__device__ inline unsigned short f16bits(float v) {
    union { __half h; unsigned short u; } a;
    a.h = __float2half_rn(v);
    return a.u;
}
__device__ inline __half2 u2h2(unsigned u) {
    union { unsigned u; __half2 h; } x; x.u = u; return x.h;
}
__device__ inline unsigned h22u(__half2 h) {
    union { unsigned u; __half2 h; } x; x.h = h; return x.u;
}

// also zeroes gcur (fused former zero_int_kernel)
__global__ void detect_kernel(const void* x, const void* ei, int* flags, int* gcur) {
    int t = threadIdx.x;  // 64 threads
    for (int i = t; i < NBUK; i += 64) gcur[i] = 0;
    float v = fabsf(__bfloat162float(((const __hip_bfloat16*)x)[t]));
    bool inband = (v >= 0.00390625f && v <= 16.0f);
    unsigned long long m = __ballot(inband);
    if (t == 0) {
        flags[0] = (__popcll(m) < 48) ? 1 : 0;  // fp32 misread as bf16 -> ~33/64 in band
        const int* e32 = (const int*)ei;
        flags[1] = ((e32[1] | e32[3] | e32[5] | e32[7]) == 0) ? 1 : 0;
    }
}

// pack: bias (fp32); W0 as bf16 MFMA B-frags; W1..7 and lwB as f16 MFMA B-frags.
__global__ __launch_bounds__(256) void pack_params_kernel(const void* bs, const void* lin_w,
                                                          const void* W0, const void* Ws,
                                                          const int* __restrict__ flags,
                                                          float* __restrict__ bsf,
                                                          unsigned short* __restrict__ wpack) {
    bool f32 = flags[0] != 0;
    int gid = blockIdx.x * 256 + threadIdx.x;
    int stride = gridDim.x * 256;
    for (int idx = gid; idx < LAYERS * HID; idx += stride) bsf[idx] = ldext(bs, f32, idx);
    // layer 0 W: K=128 (KS=4), 8192 elements, bf16 (A = x is bf16)
    for (int idx = gid; idx < 8192; idx += stride) {
        int j = idx & 7, lane = (idx >> 3) & 63, rest = idx >> 9;
        int ks = rest & 3, ct = rest >> 2;
        int quad = lane >> 4, m = lane & 15;
        wpack[idx] = bf16bits(ldext(W0, f32, (size_t)(ks * 32 + quad * 8 + j) * 64 + ct * 16 + m));
    }
    // layers 1..7 W: K=64 (KS=2), 4096 each, f16 (A = h is f16)
    for (int idx = gid; idx < 7 * 4096; idx += stride) {
        int l = idx >> 12, r = idx & 4095;
        int j = r & 7, lane = (r >> 3) & 63, rest = r >> 9;
        int ks = rest & 1, ct = rest >> 1;
        int quad = lane >> 4, m = lane & 15;
        wpack[8192 + idx] = f16bits(
            ldext(Ws, f32, (size_t)l * 4096 + (size_t)(ks * 32 + quad * 8 + j) * 64 + ct * 16 + m));
    }
    // lwB: 8 layers x 3072 (3 ct x 2 ks x 64 lanes x 8), f16
    for (int idx = gid; idx < LAYERS * 3072; idx += stride) {
        int l = idx / 3072, r = idx % 3072;
        int j = r & 7, lane = (r >> 3) & 63, rest = r >> 9;
        int ks = rest & 1, ct = rest >> 1;
        int quad = lane >> 4, m = lane & 15;
        int col = ct * 16 + m;
        int k = l * 64 + ks * 32 + quad * 8 + j;
        wpack[36864 + idx] = (col < OUT_DIM)
            ? f16bits(ldext(lin_w, f32, (size_t)k * OUT_DIM + col)) : (unsigned short)0;
    }
}

// ---------- phase 1: LDS counting-sort append into per-bucket FIFOs ----------
__global__ __launch_bounds__(256) void bucket1_kernel(const void* ei_raw, const int* __restrict__ flags,
                                                      int* __restrict__ gcur, int* __restrict__ fifo) {
    __shared__ int lhist[NBUK];
    __shared__ int lbase[NBUK];
    bool is64 = flags[1] != 0;
    int t = threadIdx.x;
    for (int i = t; i < NBUK; i += 256) lhist[i] = 0;
    __syncthreads();
    int e0 = blockIdx.x * S1_EPB;
    int rec[8], bk[8], loff[8];
#pragma unroll
    for (int j = 0; j < 8; j++) {
        int e = e0 + j * 256 + t;
        bk[j] = -1;
        if (e < N_EDGES) {
            int s = load_edge(ei_raw, is64, e);
            int d = load_edge(ei_raw, is64, (long long)N_EDGES + e);
            int b = d >> 9;
            bk[j] = b;
            rec[j] = ((d & 511) << 17) | s;
            loff[j] = atomicAdd(&lhist[b], 1);
        }
    }
    __syncthreads();
    for (int i = t; i < NBUK; i += 256)
        lbase[i] = (lhist[i] > 0) ? atomicAdd(&gcur[i], lhist[i]) : 0;
    __syncthreads();
#pragma unroll
    for (int j = 0; j < 8; j++) {
        if (bk[j] >= 0) {
            int idx = lbase[bk[j]] + loff[j];
            if (idx < BUK_CAP) fifo[bk[j] * BUK_CAP + idx] = rec[j];
        }
    }
}

// ---------- degree + dis from FIFO (LDS counters; fused former calc_dis) ----------
__global__ __launch_bounds__(256) void deg_fifo_kernel(const int* __restrict__ gcur,
                                                       const int* __restrict__ fifo,
                                                       int* __restrict__ deg,
                                                       float* __restrict__ dis) {
    __shared__ int ldeg[512];
    int b = blockIdx.x, t = threadIdx.x;
    ldeg[t] = 0;
    ldeg[t + 256] = 0;
    __syncthreads();
    int cnt = min(gcur[b], BUK_CAP);
    for (int i = t; i < cnt; i += 256)
        atomicAdd(&ldeg[fifo[b * BUK_CAP + i] >> 17], 1);
    __syncthreads();
    int n0 = b * 512 + t;
    if (n0 < N_NODES) {
        int d = ldeg[t];
        deg[n0] = d;
        dis[n0] = rsqrtf((float)(d + 1));  // +1 self-loop
    }
    if (n0 + 256 < N_NODES) {
        int d = ldeg[t + 256];
        deg[n0 + 256] = d;
        dis[n0 + 256] = rsqrtf((float)(d + 1));
    }
}

// exclusive scan of deg -> row (3-kernel, 1024 elems/block)
__global__ __launch_bounds__(256) void scan1_kernel(const int* __restrict__ deg, int* __restrict__ row,
                                                    int* __restrict__ bsums) {
    __shared__ int sd[256];
    int t = threadIdx.x;
    int base = blockIdx.x * 1024 + t * 4;
    int v[4];
#pragma unroll
    for (int j = 0; j < 4; j++) {
        int idx = base + j;
        v[j] = (idx < N_NODES) ? deg[idx] : 0;
    }
    int s4 = v[0] + v[1] + v[2] + v[3];
    sd[t] = s4;
    __syncthreads();
    for (int off = 1; off < 256; off <<= 1) {
        int x = (t >= off) ? sd[t - off] : 0;
        __syncthreads();
        sd[t] += x;
        __syncthreads();
    }
    int run = sd[t] - s4;  // exclusive
#pragma unroll
    for (int j = 0; j < 4; j++) {
        int idx = base + j;
        if (idx < N_NODES) row[idx] = run;
        run += v[j];
    }
    if (t == 255) bsums[blockIdx.x] = sd[255];
}

__global__ void scan2_kernel(int* bsums) {
    __shared__ int sd[128];
    int t = threadIdx.x;
    int v = (t < SCAN_NB) ? bsums[t] : 0;
    sd[t] = v;
    __syncthreads();
    for (int off = 1; off < 128; off <<= 1) {
        int x = (t >= off) ? sd[t - off] : 0;
        __syncthreads();
        sd[t] += x;
        __syncthreads();
    }
    if (t < SCAN_NB) bsums[t] = sd[t] - v;  // exclusive block offsets
}

__global__ __launch_bounds__(256) void scan3_kernel(int* __restrict__ row, const int* __restrict__ bsums) {
    int i = blockIdx.x * 256 + threadIdx.x;
    if (i < N_NODES) row[i] += bsums[i >> 10];
    if (i == 0) row[N_NODES] = N_EDGES;
}

// ---------- phase 2: per-bucket scatter to final CSR with LDS cursors ----------
__global__ __launch_bounds__(256) void bucket2_kernel(const int* __restrict__ gcur,
                                                      const int* __restrict__ fifo,
                                                      const int* __restrict__ row,
                                                      int* __restrict__ csr_src) {
    __shared__ int lcur[512];
    int b = blockIdx.x, t = threadIdx.x;
    int n0 = b * 512 + t;
    lcur[t] = row[min(n0, N_NODES)];
    lcur[t + 256] = row[min(n0 + 256, N_NODES)];
    __syncthreads();
    int cnt = min(gcur[b], BUK_CAP);
    for (int i = t; i < cnt; i += 256) {
        int r = fifo[b * BUK_CAP + i];
        int pos = atomicAdd(&lcur[r >> 17], 1);
        csr_src[pos] = r & 0x1FFFF;
    }
}

// ---------- MFMA matmul: t0s (f16, 4 quarter-slices, dis-prescaled) = dis .* (h @ W) ----------
// ABF16: A/wW are bf16 (layer 0, A = x, converted in-register if fp32); else f16 (A = h).
// JK: 0 = none, 1 = out_acc = h @ lwB, 2 = out_acc += h @ lwB (exclusive per node)
template <int KS, int JK, bool ABF16>
__global__ __launch_bounds__(256) void mm_mfma_kernel(const void* __restrict__ h0,
                                                      const void* __restrict__ h1,
                                                      const int* __restrict__ flags,
                                                      const unsigned short* __restrict__ wW,
                                                      const unsigned short* __restrict__ wJ,
                                                      const float* __restrict__ dis,
                                                      __half* __restrict__ t0s,
                                                      float* __restrict__ out_acc) {
    constexpr int K = KS * 32;
    int wave = threadIdx.x >> 6, lane = threadIdx.x & 63;
    int quad = lane >> 4, m = lane & 15;
    int nb = blockIdx.x * 64 + wave * 16;
    int ra = nb + m;
    if (ra > N_NODES - 1) ra = N_NODES - 1;  // clamp tail (avoids OOB read)
    short8 a[KS];
    if constexpr (ABF16) {
        if (flags[0]) {
            // fp32 input: load floats, convert to bf16 in-register (replaces convert_x pass)
            const float* xr = (const float*)h1 + (size_t)ra * K + quad * 8;
#pragma unroll
            for (int ks = 0; ks < KS; ks++) {
                float4 f0 = *(const float4*)(xr + ks * 32);
                float4 f1 = *(const float4*)(xr + ks * 32 + 4);
                short8 v;
                v[0] = (short)bf16bits(f0.x); v[1] = (short)bf16bits(f0.y);
                v[2] = (short)bf16bits(f0.z); v[3] = (short)bf16bits(f0.w);
                v[4] = (short)bf16bits(f1.x); v[5] = (short)bf16bits(f1.y);
                v[6] = (short)bf16bits(f1.z); v[7] = (short)bf16bits(f1.w);
                a[ks] = v;
            }
        } else {
            const short* hrow = (const short*)h0 + (size_t)ra * K + quad * 8;
#pragma unroll
            for (int ks = 0; ks < KS; ks++) a[ks] = *(const short8*)(hrow + ks * 32);
        }
    } else {
        const short* hrow = (const short*)h0 + (size_t)ra * K + quad * 8;
#pragma unroll
        for (int ks = 0; ks < KS; ks++) a[ks] = *(const short8*)(hrow + ks * 32);
    }
    float dr[4];
#pragma unroll
    for (int r = 0; r < 4; r++) {
        int rw = nb + quad * 4 + r;
        dr[r] = dis[rw < N_NODES ? rw : (N_NODES - 1)];
    }
#pragma unroll
    for (int ct = 0; ct < 4; ct++) {
        float4v acc = (float4v){0.f, 0.f, 0.f, 0.f};
#pragma unroll
        for (int ks = 0; ks < KS; ks++) {
            short8 b = *(const short8*)(wW + ((ct * KS + ks) * 64 + lane) * 8);
            if constexpr (ABF16)
                acc = __builtin_amdgcn_mfma_f32_16x16x32_bf16(a[ks], b, acc, 0, 0, 0);
            else
                acc = __builtin_amdgcn_mfma_f32_16x16x32_f16(
                    __builtin_bit_cast(half8, a[ks]), __builtin_bit_cast(half8, b), acc, 0, 0, 0);
        }
        // quarter-slice ct holds features ct*16..ct*16+15
#pragma unroll
        for (int r = 0; r < 4; r++) {
            t0s[(size_t)ct * T0SL4 + (size_t)(nb + quad * 4 + r) * 16 + m] =
                __float2half(acc[r] * dr[r]);
        }
    }
    if (JK) {
#pragma unroll
        for (int ct = 0; ct < 3; ct++) {
            float4v j = (float4v){0.f, 0.f, 0.f, 0.f};
#pragma unroll
            for (int ks = 0; ks < KS; ks++) {
                short8 b = *(const short8*)(wJ + ((ct * KS + ks) * 64 + lane) * 8);
                if constexpr (ABF16)
                    j = __builtin_amdgcn_mfma_f32_16x16x32_bf16(a[ks], b, j, 0, 0, 0);
                else
                    j = __builtin_amdgcn_mfma_f32_16x16x32_f16(
                        __builtin_bit_cast(half8, a[ks]), __builtin_bit_cast(half8, b), j, 0, 0, 0);
            }
            int col = ct * 16 + m;
            if (col < OUT_DIM) {
#pragma unroll
                for (int r = 0; r < 4; r++) {
                    int rw = nb + quad * 4 + r;
                    if (rw < N_NODES) {
                        size_t o = (size_t)rw * OUT_DIM + col;
                        if (JK == 1) out_acc[o] = j[r];
                        else out_acc[o] += j[r];
                    }
                }
            }
        }
    }
}

// ---------- aggregation: 4 XCD-affine quarter-slices, staged csr, 4 nodes/wave ----------
// ILP restructure: per pass, ALL gather rounds (self + 3 edge rounds = up to 24 edges/node)
// are issued branchlessly BEFORE any accumulate (masked hfma2), so the fully-unrolled
// 8-pass body is straight-line loads the scheduler overlaps across passes. Rare deg>24
// nodes take a short tail loop; bucket overflow (never for this graph: cap +22 sigma)
// takes a block-uniform slow path identical to the old code.
__global__ __launch_bounds__(256, 6) void agg_kernel(const __half* __restrict__ t0s,
                                                     const int* __restrict__ row,
                                                     const int* __restrict__ csr_src,
                                                     const float* __restrict__ dis,
                                                     const float* __restrict__ bsf,   // this layer, 64 f32
                                                     __half* __restrict__ h) {
    __shared__ int lrow[AGG_N + 1];
    __shared__ int lcsr[AGG_CAP];
    int t = threadIdx.x;
    int s = blockIdx.x & 3;
    int nb = (blockIdx.x >> 2) * AGG_N;
    const __half* tsl = t0s + (size_t)s * T0SL4;

    for (int i = t; i <= AGG_N; i += 256) {
        int n = nb + i;
        lrow[i] = row[n > N_NODES ? N_NODES : n];
    }
    __syncthreads();
    int rs0 = lrow[0];
    int cnt_raw = lrow[AGG_N] - rs0;
    int cnt = min(cnt_raw, AGG_CAP);
    for (int i = t; i < cnt; i += 256)
        lcsr[i] = __builtin_nontemporal_load(&csr_src[rs0 + i]);
    __syncthreads();

    int wave = t >> 6, lane = t & 63;
    int ns = lane >> 4, ep = (lane >> 1) & 7, fp = lane & 1;
    const __half2 h2one = __floats2half2_rn(1.f, 1.f);
    const __half2 h2zero = __floats2half2_rn(0.f, 0.f);

    if (cnt_raw <= AGG_CAP) {
#pragma unroll
        for (int pass = 0; pass < AGG_N / 16; pass++) {
            int nl = pass * 16 + wave * 4 + ns;
            int node = nb + nl;
            bool valid = node < N_NODES;
            int safe = valid ? node : (N_NODES - 1);
            int rs = valid ? lrow[nl] : 0;
            int re = valid ? lrow[nl + 1] : 0;
            int p0 = rs + ep, p1 = p0 + 8, p2 = p1 + 8;
            bool b0 = p0 < re, b1 = p1 < re, b2 = p2 < re;
            bool bS = valid && (ep == 0);
            // branchless LDS index (clamped; masked later) then 4 gathers in flight
            int se0 = lcsr[min(p0 - rs0, AGG_CAP - 1)];
            int se1 = lcsr[min(p1 - rs0, AGG_CAP - 1)];
            int se2 = lcsr[min(p2 - rs0, AGG_CAP - 1)];
            se0 = b0 ? se0 : safe;
            se1 = b1 ? se1 : safe;
            se2 = b2 ? se2 : safe;
            uint4 vS = *(const uint4*)(tsl + (size_t)safe * 16 + fp * 8);
            uint4 v0 = *(const uint4*)(tsl + (size_t)se0 * 16 + fp * 8);
            uint4 v1 = *(const uint4*)(tsl + (size_t)se1 * 16 + fp * 8);
            uint4 v2 = *(const uint4*)(tsl + (size_t)se2 * 16 + fp * 8);
            __half2 mS = bS ? h2one : h2zero;
            __half2 m0 = b0 ? h2one : h2zero;
            __half2 m1 = b1 ? h2one : h2zero;
            __half2 m2 = b2 ? h2one : h2zero;
            __half2 a2[4];
            a2[0] = __hmul2(u2h2(vS.x), mS);
            a2[1] = __hmul2(u2h2(vS.y), mS);
            a2[2] = __hmul2(u2h2(vS.z), mS);
            a2[3] = __hmul2(u2h2(vS.w), mS);
            a2[0] = __hfma2(u2h2(v0.x), m0, a2[0]);
            a2[1] = __hfma2(u2h2(v0.y), m0, a2[1]);
            a2[2] = __hfma2(u2h2(v0.z), m0, a2[2]);
            a2[3] = __hfma2(u2h2(v0.w), m0, a2[3]);
            a2[0] = __hfma2(u2h2(v1.x), m1, a2[0]);
            a2[1] = __hfma2(u2h2(v1.y), m1, a2[1]);
            a2[2] = __hfma2(u2h2(v1.z), m1, a2[2]);
            a2[3] = __hfma2(u2h2(v1.w), m1, a2[3]);
            a2[0] = __hfma2(u2h2(v2.x), m2, a2[0]);
            a2[1] = __hfma2(u2h2(v2.y), m2, a2[1]);
            a2[2] = __hfma2(u2h2(v2.z), m2, a2[2]);
            a2[3] = __hfma2(u2h2(v2.w), m2, a2[3]);
            for (int p = p2 + 8; p < re; p += 8) {  // rare: deg > 24
                int se = lcsr[p - rs0];
                uint4 v = *(const uint4*)(tsl + (size_t)se * 16 + fp * 8);
                a2[0] = __hadd2(a2[0], u2h2(v.x));
                a2[1] = __hadd2(a2[1], u2h2(v.y));
                a2[2] = __hadd2(a2[2], u2h2(v.z));
                a2[3] = __hadd2(a2[3], u2h2(v.w));
            }
            // reduce over ep (lane bits 1..3)
#pragma unroll
            for (int st = 2; st <= 8; st <<= 1) {
#pragma unroll
                for (int r = 0; r < 4; r++)
                    a2[r] = __hadd2(a2[r], u2h2(__shfl_xor(h22u(a2[r]), st)));
            }
            if (valid && ep == 0) {
                float di = dis[node];
                const float* bb = bsf + s * 16 + fp * 8;
                float a[8];
#pragma unroll
                for (int r = 0; r < 4; r++) {
                    a[2 * r]     = __low2float(a2[r]);
                    a[2 * r + 1] = __high2float(a2[r]);
                }
#pragma unroll
                for (int j = 0; j < 8; j++) a[j] = fmaxf(di * a[j] + bb[j], 0.f);
                uint4 pv;
                pv.x = h22u(__floats2half2_rn(a[0], a[1]));
                pv.y = h22u(__floats2half2_rn(a[2], a[3]));
                pv.z = h22u(__floats2half2_rn(a[4], a[5]));
                pv.w = h22u(__floats2half2_rn(a[6], a[7]));
                *(uint4*)(h + (size_t)node * 64 + s * 16 + fp * 8) = pv;
            }
        }
    } else {
        // slow path: staged-LDS overflow (block-uniform, essentially never taken)
#pragma unroll
        for (int pass = 0; pass < AGG_N / 16; pass++) {
            int nl = pass * 16 + wave * 4 + ns;
            int node = nb + nl;
            bool valid = node < N_NODES;
            int rs = valid ? lrow[nl] : 0;
            int re = valid ? lrow[nl + 1] : 0;
            __half2 a2[4];
#pragma unroll
            for (int r = 0; r < 4; r++) a2[r] = h2zero;
            if (valid && ep == 0) {
                uint4 v = *(const uint4*)(tsl + (size_t)node * 16 + fp * 8);
                a2[0] = __hadd2(a2[0], u2h2(v.x));
                a2[1] = __hadd2(a2[1], u2h2(v.y));
                a2[2] = __hadd2(a2[2], u2h2(v.z));
                a2[3] = __hadd2(a2[3], u2h2(v.w));
            }
            for (int base = rs; base + ep < re; base += 8) {
                int idx = base + ep - rs0;
                int se = (idx < AGG_CAP) ? lcsr[idx] : csr_src[base + ep];
                uint4 v = *(const uint4*)(tsl + (size_t)se * 16 + fp * 8);
                a2[0] = __hadd2(a2[0], u2h2(v.x));
                a2[1] = __hadd2(a2[1], u2h2(v.y));
                a2[2] = __hadd2(a2[2], u2h2(v.z));
                a2[3] = __hadd2(a2[3], u2h2(v.w));
            }
#pragma unroll
            for (int st = 2; st <= 8; st <<= 1) {
#pragma unroll
                for (int r = 0; r < 4; r++)
                    a2[r] = __hadd2(a2[r], u2h2(__shfl_xor(h22u(a2[r]), st)));
            }
            if (valid && ep == 0) {
                float di = dis[node];
                const float* bb = bsf + s * 16 + fp * 8;
                float a[8];
#pragma unroll
                for (int r = 0; r < 4; r++) {
                    a[2 * r]     = __low2float(a2[r]);
                    a[2 * r + 1] = __high2float(a2[r]);
                }
#pragma unroll
                for (int j = 0; j < 8; j++) a[j] = fmaxf(di * a[j] + bb[j], 0.f);
                uint4 pv;
                pv.x = h22u(__floats2half2_rn(a[0], a[1]));
                pv.y = h22u(__floats2half2_rn(a[2], a[3]));
                pv.z = h22u(__floats2half2_rn(a[4], a[5]));
                pv.w = h22u(__floats2half2_rn(a[6], a[7]));
                *(uint4*)(h + (size_t)node * 64 + s * 16 + fp * 8) = pv;
            }
        }
    }
}

// ---------- final: out = out_acc + h7 @ lwB7 + lin_b ----------
__global__ __launch_bounds__(256) void jk_final_kernel(const __half* __restrict__ h,
                                                       const unsigned short* __restrict__ wJ,
                                                       const float* __restrict__ out_acc,
                                                       const void* __restrict__ lin_b,
                                                       const int* __restrict__ flags,
                                                       void* __restrict__ d_out) {
    bool f32 = flags[0] != 0;
    int wave = threadIdx.x >> 6, lane = threadIdx.x & 63;
    int quad = lane >> 4, m = lane & 15;
    int nb = blockIdx.x * 64 + wave * 16;
    int ra = nb + m;
    if (ra > N_NODES - 1) ra = N_NODES - 1;
    const short* hrow = (const short*)(h + (size_t)ra * 64) + quad * 8;
    short8 a0 = *(const short8*)(hrow);
    short8 a1 = *(const short8*)(hrow + 32);
#pragma unroll
    for (int ct = 0; ct < 3; ct++) {
        float4v j = (float4v){0.f, 0.f, 0.f, 0.f};
        short8 b0 = *(const short8*)(wJ + ((ct * 2 + 0) * 64 + lane) * 8);
        short8 b1 = *(const short8*)(wJ + ((ct * 2 + 1) * 64 + lane) * 8);
        j = __builtin_amdgcn_mfma_f32_16x16x32_f16(
            __builtin_bit_cast(half8, a0), __builtin_bit_cast(half8, b0), j, 0, 0, 0);
        j = __builtin_amdgcn_mfma_f32_16x16x32_f16(
            __builtin_bit_cast(half8, a1), __builtin_bit_cast(half8, b1), j, 0, 0, 0);
        int col = ct * 16 + m;
        if (col < OUT_DIM) {
            float lb = ldext(lin_b, f32, col);
#pragma unroll
            for (int r = 0; r < 4; r++) {
                int rw = nb + quad * 4 + r;
                if (rw < N_NODES) {
                    float v = out_acc[(size_t)rw * OUT_DIM + col] + j[r] + lb;
                    if (f32) ((float*)d_out)[(size_t)rw * OUT_DIM + col] = v;
                    else ((__hip_bfloat16*)d_out)[(size_t)rw * OUT_DIM + col] = __float2bfloat16(v);
                }
            }
        }
    }
}

extern "C" void kernel_launch(void* const* d_in, const int* in_sizes, int n_in,
                              void* d_out, int out_size, void* d_ws, size_t ws_size,
                              hipStream_t stream) {
    const void* x     = d_in[0];
    const void* W0    = d_in[1];
    const void* Ws    = d_in[2];
    const void* bs    = d_in[3];
    const void* lin_w = d_in[4];
    const void* lin_b = d_in[5];
    const void* ei    = d_in[6];

    size_t off = 0;
    auto alloc = [&](size_t bytes) -> void* {
        void* p = (char*)d_ws + off;
        off += (bytes + 511) & ~(size_t)511;
        return p;
    };
    int*   flags   = (int*)alloc(512);
    float* dis     = (float*)alloc((size_t)(N_NODES + 64) * 4);
    int*   deg     = (int*)alloc((size_t)N_NODES * 4);
    int*   row     = (int*)alloc((size_t)(N_NODES + 1) * 4);
    int*   bsums   = (int*)alloc(128 * 4);
    int*   gcur    = (int*)alloc((size_t)NBUK * 4);
    int*   fifo    = (int*)alloc((size_t)NBUK * BUK_CAP * 4);   // 9.4 MB
    int*   csr_src = (int*)alloc((size_t)N_EDGES * 4);
    __half* t0s = (__half*)alloc((size_t)4 * T0SL4 * 2);
    __half* h   = (__half*)alloc((size_t)(N_NODES + 32) * HID * 2);
    float* out_acc = (float*)alloc((size_t)N_NODES * OUT_DIM * 4);
    float* bsf     = (float*)alloc((size_t)LAYERS * HID * 4);
    unsigned short* wpack = (unsigned short*)alloc((size_t)61440 * 2);

    const int nblkN  = (N_NODES + 255) / 256;
    const int nblkS1 = (N_EDGES + S1_EPB - 1) / S1_EPB;   // 782
    const int nblkMM = (N_NODES + 63) / 64;               // 1563
    const int nblkAG = ((N_NODES + AGG_N - 1) / AGG_N) * 4;  // 782*4 = 3128

    detect_kernel<<<1, 64, 0, stream>>>(x, ei, flags, gcur);
    pack_params_kernel<<<80, 256, 0, stream>>>(bs, lin_w, W0, Ws, flags, bsf, wpack);
    bucket1_kernel<<<nblkS1, 256, 0, stream>>>(ei, flags, gcur, fifo);
    deg_fifo_kernel<<<NBUK, 256, 0, stream>>>(gcur, fifo, deg, dis);
    scan1_kernel<<<SCAN_NB, 256, 0, stream>>>(deg, row, bsums);
    scan2_kernel<<<1, 128, 0, stream>>>(bsums);
    scan3_kernel<<<nblkN, 256, 0, stream>>>(row, bsums);
    bucket2_kernel<<<NBUK, 256, 0, stream>>>(gcur, fifo, row, csr_src);

    const unsigned short* wJ0 = wpack + 36864;
    for (int l = 0; l < LAYERS; l++) {
        if (l == 0) {
            mm_mfma_kernel<4, 0, true><<<nblkMM, 256, 0, stream>>>(
                x, x, flags, wpack, nullptr, dis, t0s, nullptr);
        } else if (l == 1) {
            mm_mfma_kernel<2, 1, false><<<nblkMM, 256, 0, stream>>>(
                h, h, flags, wpack + 8192, wJ0, dis, t0s, out_acc);
        } else {
            mm_mfma_kernel<2, 2, false><<<nblkMM, 256, 0, stream>>>(
                h, h, flags, wpack + 8192 + (size_t)(l - 1) * 4096,
                wJ0 + (size_t)(l - 1) * 3072, dis, t0s, out_acc);
        }
        agg_kernel<<<nblkAG, 256, 0, stream>>>(t0s, row, csr_src, dis,
                                               bsf + (size_t)l * HID, h);
    }
    jk_final_kernel<<<nblkMM, 256, 0, stream>>>(h, wJ0 + (size_t)7 * 3072, out_acc,
                                                lin_b, flags, d_out);
}

// Round 2
// 633.557 us; speedup vs baseline: 1.1307x; 1.1228x over previous
//
#include <hip/hip_runtime.h>
#include <hip/hip_bf16.h>
#include <hip/hip_fp16.h>

#define N_NODES 100000
#define N_EDGES 1600000
#define HID     64
#define LAYERS  8
#define OUT_DIM 40
#define SCAN_NB 98   // ceil(100000/1024)
#define T0SL4   ((size_t)(N_NODES + 32) * 16)   // elements per t0 quarter-slice (16 feats)
#define NBUK    196      // ceil(100000/512) buckets of 512 nodes
#define BUK_CAP 12000    // avg 8163/bucket -> huge sigma headroom
#define S1_EPB  2048     // edges per bucket1 block (256 thr x 8)
#define AGG_N   128      // nodes per agg block
#define AGG_CAP 3072     // staged csr entries (mean 2048, +22 sigma), 12KB LDS

typedef __attribute__((ext_vector_type(8))) short short8;
typedef __attribute__((ext_vector_type(8))) _Float16 half8;
typedef __attribute__((ext_vector_type(4))) float float4v;

// ---------- runtime environment hedges ----------
// flags[0] = 1 if feature inputs are float32 (else bf16)
// flags[1] = 1 if edge_index is int64 (else int32)
__device__ inline float ldext(const void* p, bool f32, size_t i) {
    return f32 ? ((const float*)p)[i]
               : __bfloat162float(((const __hip_bfloat16*)p)[i]);
}
__device__ inline int load_edge(const void* raw, bool is64, long long idx) {
    return is64 ? (int)((const long long*)raw)[idx] : ((const int*)raw)[idx];
}
__device__ inline unsigned pack_bf16x2(float lo, float hi) {
    union { __hip_bfloat16 b; unsigned short u; } a, b;
    a.b = __float2bfloat16(lo);
    b.b = __float2bfloat16(hi);
    return ((unsigned)b.u << 16) | a.u;
}
__device__ inline unsigned short bf16bits(float v) {
    union { __hip_bfloat16 b; unsigned short u; } a;
    a.b = __float2bfloat16(v);
    return a.u;
}
__device__ inline unsigned short f16bits(float v) {
    union { __half h; unsigned short u; } a;
    a.h = __float2half_rn(v);
    return a.u;
}
__device__ inline __half2 u2h2(unsigned u) {
    union { unsigned u; __half2 h; } x; x.u = u; return x.h;
}
__device__ inline unsigned h22u(__half2 h) {
    union { unsigned u; __half2 h; } x; x.h = h; return x.u;
}

// DPP lane-rotation move (VALU pipe; replaces ds-pipe shuffles in the ep-reduce).
// 0x4E = quad_perm[2,3,0,1] (xor 2); 0x124 = row_ror:4; 0x128 = row_ror:8.
// Rotations within a row of 16 are valid for a commutative sum over lane bits 1..3
// and preserve bit 0 (fp parity).
template <int CTRL>
__device__ inline unsigned dppu(unsigned v) {
    return (unsigned)__builtin_amdgcn_update_dpp((int)v, (int)v, CTRL, 0xF, 0xF, false);
}

// also zeroes gcur (fused former zero_int_kernel)
__global__ void detect_kernel(const void* x, const void* ei, int* flags, int* gcur) {
    int t = threadIdx.x;  // 64 threads
    for (int i = t; i < NBUK; i += 64) gcur[i] = 0;
    float v = fabsf(__bfloat162float(((const __hip_bfloat16*)x)[t]));
    bool inband = (v >= 0.00390625f && v <= 16.0f);
    unsigned long long m = __ballot(inband);
    if (t == 0) {
        flags[0] = (__popcll(m) < 48) ? 1 : 0;  // fp32 misread as bf16 -> ~33/64 in band
        const int* e32 = (const int*)ei;
        flags[1] = ((e32[1] | e32[3] | e32[5] | e32[7]) == 0) ? 1 : 0;
    }
}

// pack: bias (fp32); W0 as bf16 MFMA B-frags; W1..7 and lwB as f16 MFMA B-frags.
__global__ __launch_bounds__(256) void pack_params_kernel(const void* bs, const void* lin_w,
                                                          const void* W0, const void* Ws,
                                                          const int* __restrict__ flags,
                                                          float* __restrict__ bsf,
                                                          unsigned short* __restrict__ wpack) {
    bool f32 = flags[0] != 0;
    int gid = blockIdx.x * 256 + threadIdx.x;
    int stride = gridDim.x * 256;
    for (int idx = gid; idx < LAYERS * HID; idx += stride) bsf[idx] = ldext(bs, f32, idx);
    // layer 0 W: K=128 (KS=4), 8192 elements, bf16 (A = x is bf16)
    for (int idx = gid; idx < 8192; idx += stride) {
        int j = idx & 7, lane = (idx >> 3) & 63, rest = idx >> 9;
        int ks = rest & 3, ct = rest >> 2;
        int quad = lane >> 4, m = lane & 15;
        wpack[idx] = bf16bits(ldext(W0, f32, (size_t)(ks * 32 + quad * 8 + j) * 64 + ct * 16 + m));
    }
    // layers 1..7 W: K=64 (KS=2), 4096 each, f16 (A = h is f16)
    for (int idx = gid; idx < 7 * 4096; idx += stride) {
        int l = idx >> 12, r = idx & 4095;
        int j = r & 7, lane = (r >> 3) & 63, rest = r >> 9;
        int ks = rest & 1, ct = rest >> 1;
        int quad = lane >> 4, m = lane & 15;
        wpack[8192 + idx] = f16bits(
            ldext(Ws, f32, (size_t)l * 4096 + (size_t)(ks * 32 + quad * 8 + j) * 64 + ct * 16 + m));
    }
    // lwB: 8 layers x 3072 (3 ct x 2 ks x 64 lanes x 8), f16
    for (int idx = gid; idx < LAYERS * 3072; idx += stride) {
        int l = idx / 3072, r = idx % 3072;
        int j = r & 7, lane = (r >> 3) & 63, rest = r >> 9;
        int ks = rest & 1, ct = rest >> 1;
        int quad = lane >> 4, m = lane & 15;
        int col = ct * 16 + m;
        int k = l * 64 + ks * 32 + quad * 8 + j;
        wpack[36864 + idx] = (col < OUT_DIM)
            ? f16bits(ldext(lin_w, f32, (size_t)k * OUT_DIM + col)) : (unsigned short)0;
    }
}

// ---------- phase 1: LDS counting-sort append into per-bucket FIFOs ----------
__global__ __launch_bounds__(256) void bucket1_kernel(const void* ei_raw, const int* __restrict__ flags,
                                                      int* __restrict__ gcur, int* __restrict__ fifo) {
    __shared__ int lhist[NBUK];
    __shared__ int lbase[NBUK];
    bool is64 = flags[1] != 0;
    int t = threadIdx.x;
    for (int i = t; i < NBUK; i += 256) lhist[i] = 0;
    __syncthreads();
    int e0 = blockIdx.x * S1_EPB;
    int rec[8], bk[8], loff[8];
#pragma unroll
    for (int j = 0; j < 8; j++) {
        int e = e0 + j * 256 + t;
        bk[j] = -1;
        if (e < N_EDGES) {
            int s = load_edge(ei_raw, is64, e);
            int d = load_edge(ei_raw, is64, (long long)N_EDGES + e);
            int b = d >> 9;
            bk[j] = b;
            rec[j] = ((d & 511) << 17) | s;
            loff[j] = atomicAdd(&lhist[b], 1);
        }
    }
    __syncthreads();
    for (int i = t; i < NBUK; i += 256)
        lbase[i] = (lhist[i] > 0) ? atomicAdd(&gcur[i], lhist[i]) : 0;
    __syncthreads();
#pragma unroll
    for (int j = 0; j < 8; j++) {
        if (bk[j] >= 0) {
            int idx = lbase[bk[j]] + loff[j];
            if (idx < BUK_CAP) fifo[bk[j] * BUK_CAP + idx] = rec[j];
        }
    }
}

// ---------- degree + dis from FIFO (LDS counters; fused former calc_dis) ----------
__global__ __launch_bounds__(256) void deg_fifo_kernel(const int* __restrict__ gcur,
                                                       const int* __restrict__ fifo,
                                                       int* __restrict__ deg,
                                                       float* __restrict__ dis) {
    __shared__ int ldeg[512];
    int b = blockIdx.x, t = threadIdx.x;
    ldeg[t] = 0;
    ldeg[t + 256] = 0;
    __syncthreads();
    int cnt = min(gcur[b], BUK_CAP);
    for (int i = t; i < cnt; i += 256)
        atomicAdd(&ldeg[fifo[b * BUK_CAP + i] >> 17], 1);
    __syncthreads();
    int n0 = b * 512 + t;
    if (n0 < N_NODES) {
        int d = ldeg[t];
        deg[n0] = d;
        dis[n0] = rsqrtf((float)(d + 1));  // +1 self-loop
    }
    if (n0 + 256 < N_NODES) {
        int d = ldeg[t + 256];
        deg[n0 + 256] = d;
        dis[n0 + 256] = rsqrtf((float)(d + 1));
    }
}

// exclusive scan of deg -> row (3-kernel, 1024 elems/block)
__global__ __launch_bounds__(256) void scan1_kernel(const int* __restrict__ deg, int* __restrict__ row,
                                                    int* __restrict__ bsums) {
    __shared__ int sd[256];
    int t = threadIdx.x;
    int base = blockIdx.x * 1024 + t * 4;
    int v[4];
#pragma unroll
    for (int j = 0; j < 4; j++) {
        int idx = base + j;
        v[j] = (idx < N_NODES) ? deg[idx] : 0;
    }
    int s4 = v[0] + v[1] + v[2] + v[3];
    sd[t] = s4;
    __syncthreads();
    for (int off = 1; off < 256; off <<= 1) {
        int x = (t >= off) ? sd[t - off] : 0;
        __syncthreads();
        sd[t] += x;
        __syncthreads();
    }
    int run = sd[t] - s4;  // exclusive
#pragma unroll
    for (int j = 0; j < 4; j++) {
        int idx = base + j;
        if (idx < N_NODES) row[idx] = run;
        run += v[j];
    }
    if (t == 255) bsums[blockIdx.x] = sd[255];
}

__global__ void scan2_kernel(int* bsums) {
    __shared__ int sd[128];
    int t = threadIdx.x;
    int v = (t < SCAN_NB) ? bsums[t] : 0;
    sd[t] = v;
    __syncthreads();
    for (int off = 1; off < 128; off <<= 1) {
        int x = (t >= off) ? sd[t - off] : 0;
        __syncthreads();
        sd[t] += x;
        __syncthreads();
    }
    if (t < SCAN_NB) bsums[t] = sd[t] - v;  // exclusive block offsets
}

__global__ __launch_bounds__(256) void scan3_kernel(int* __restrict__ row, const int* __restrict__ bsums) {
    int i = blockIdx.x * 256 + threadIdx.x;
    if (i < N_NODES) row[i] += bsums[i >> 10];
    if (i == 0) row[N_NODES] = N_EDGES;
}

// ---------- phase 2: per-bucket scatter to final CSR with LDS cursors ----------
__global__ __launch_bounds__(256) void bucket2_kernel(const int* __restrict__ gcur,
                                                      const int* __restrict__ fifo,
                                                      const int* __restrict__ row,
                                                      int* __restrict__ csr_src) {
    __shared__ int lcur[512];
    int b = blockIdx.x, t = threadIdx.x;
    int n0 = b * 512 + t;
    lcur[t] = row[min(n0, N_NODES)];
    lcur[t + 256] = row[min(n0 + 256, N_NODES)];
    __syncthreads();
    int cnt = min(gcur[b], BUK_CAP);
    for (int i = t; i < cnt; i += 256) {
        int r = fifo[b * BUK_CAP + i];
        int pos = atomicAdd(&lcur[r >> 17], 1);
        csr_src[pos] = r & 0x1FFFF;
    }
}

// ---------- MFMA matmul: t0s (f16, 4 quarter-slices, dis-prescaled) = dis .* (h @ W) ----------
// ABF16: A/wW are bf16 (layer 0, A = x, converted in-register if fp32); else f16 (A = h).
// JK: 0 = none, 1 = out_acc = h @ lwB, 2 = out_acc += h @ lwB (exclusive per node)
template <int KS, int JK, bool ABF16>
__global__ __launch_bounds__(256) void mm_mfma_kernel(const void* __restrict__ h0,
                                                      const void* __restrict__ h1,
                                                      const int* __restrict__ flags,
                                                      const unsigned short* __restrict__ wW,
                                                      const unsigned short* __restrict__ wJ,
                                                      const float* __restrict__ dis,
                                                      __half* __restrict__ t0s,
                                                      float* __restrict__ out_acc) {
    constexpr int K = KS * 32;
    int wave = threadIdx.x >> 6, lane = threadIdx.x & 63;
    int quad = lane >> 4, m = lane & 15;
    int nb = blockIdx.x * 64 + wave * 16;
    int ra = nb + m;
    if (ra > N_NODES - 1) ra = N_NODES - 1;  // clamp tail (avoids OOB read)
    short8 a[KS];
    if constexpr (ABF16) {
        if (flags[0]) {
            // fp32 input: load floats, convert to bf16 in-register (replaces convert_x pass)
            const float* xr = (const float*)h1 + (size_t)ra * K + quad * 8;
#pragma unroll
            for (int ks = 0; ks < KS; ks++) {
                float4 f0 = *(const float4*)(xr + ks * 32);
                float4 f1 = *(const float4*)(xr + ks * 32 + 4);
                short8 v;
                v[0] = (short)bf16bits(f0.x); v[1] = (short)bf16bits(f0.y);
                v[2] = (short)bf16bits(f0.z); v[3] = (short)bf16bits(f0.w);
                v[4] = (short)bf16bits(f1.x); v[5] = (short)bf16bits(f1.y);
                v[6] = (short)bf16bits(f1.z); v[7] = (short)bf16bits(f1.w);
                a[ks] = v;
            }
        } else {
            const short* hrow = (const short*)h0 + (size_t)ra * K + quad * 8;
#pragma unroll
            for (int ks = 0; ks < KS; ks++) a[ks] = *(const short8*)(hrow + ks * 32);
        }
    } else {
        const short* hrow = (const short*)h0 + (size_t)ra * K + quad * 8;
#pragma unroll
        for (int ks = 0; ks < KS; ks++) a[ks] = *(const short8*)(hrow + ks * 32);
    }
    float dr[4];
#pragma unroll
    for (int r = 0; r < 4; r++) {
        int rw = nb + quad * 4 + r;
        dr[r] = dis[rw < N_NODES ? rw : (N_NODES - 1)];
    }
#pragma unroll
    for (int ct = 0; ct < 4; ct++) {
        float4v acc = (float4v){0.f, 0.f, 0.f, 0.f};
#pragma unroll
        for (int ks = 0; ks < KS; ks++) {
            short8 b = *(const short8*)(wW + ((ct * KS + ks) * 64 + lane) * 8);
            if constexpr (ABF16)
                acc = __builtin_amdgcn_mfma_f32_16x16x32_bf16(a[ks], b, acc, 0, 0, 0);
            else
                acc = __builtin_amdgcn_mfma_f32_16x16x32_f16(
                    __builtin_bit_cast(half8, a[ks]), __builtin_bit_cast(half8, b), acc, 0, 0, 0);
        }
        // quarter-slice ct holds features ct*16..ct*16+15
#pragma unroll
        for (int r = 0; r < 4; r++) {
            t0s[(size_t)ct * T0SL4 + (size_t)(nb + quad * 4 + r) * 16 + m] =
                __float2half(acc[r] * dr[r]);
        }
    }
    if (JK) {
#pragma unroll
        for (int ct = 0; ct < 3; ct++) {
            float4v j = (float4v){0.f, 0.f, 0.f, 0.f};
#pragma unroll
            for (int ks = 0; ks < KS; ks++) {
                short8 b = *(const short8*)(wJ + ((ct * KS + ks) * 64 + lane) * 8);
                if constexpr (ABF16)
                    j = __builtin_amdgcn_mfma_f32_16x16x32_bf16(a[ks], b, j, 0, 0, 0);
                else
                    j = __builtin_amdgcn_mfma_f32_16x16x32_f16(
                        __builtin_bit_cast(half8, a[ks]), __builtin_bit_cast(half8, b), j, 0, 0, 0);
            }
            int col = ct * 16 + m;
            if (col < OUT_DIM) {
#pragma unroll
                for (int r = 0; r < 4; r++) {
                    int rw = nb + quad * 4 + r;
                    if (rw < N_NODES) {
                        size_t o = (size_t)rw * OUT_DIM + col;
                        if (JK == 1) out_acc[o] = j[r];
                        else out_acc[o] += j[r];
                    }
                }
            }
        }
    }
}

// ---------- aggregation: 4 XCD-affine quarter-slices, staged csr, 4 nodes/wave ----------
// R1 restructure:
//  * manual 2-deep software pipeline across passes (ISSUE(p+1) before CONSUME(p),
//    ping-pong register states) so gather latency of pass p+1 overlaps the
//    accumulate/reduce/final of pass p;
//  * ep-reduce via DPP rotations on the VALU pipe (no ds-pipe shuffles);
//  * rare deg>24 tail behind a __any-guarded never-taken branch;
//  * csr staging via global_load_lds (no VGPR round-trip);
//  * di recomputed from lrow degree (no dis[] gather in the epilogue).
__global__ __launch_bounds__(256, 6) void agg_kernel(const __half* __restrict__ t0s,
                                                     const int* __restrict__ row,
                                                     const int* __restrict__ csr_src,
                                                     const float* __restrict__ bsf,   // this layer, 64 f32
                                                     __half* __restrict__ h) {
    __shared__ int lrow[AGG_N + 1];
    __shared__ __align__(16) int lcsr[AGG_CAP];
    int t = threadIdx.x;
    int s = blockIdx.x & 3;
    int nb = (blockIdx.x >> 2) * AGG_N;
    const __half* tsl = t0s + (size_t)s * T0SL4;

    for (int i = t; i <= AGG_N; i += 256) {
        int n = nb + i;
        lrow[i] = row[n > N_NODES ? N_NODES : n];
    }
    __syncthreads();
    int rs0 = lrow[0];
    int cnt_raw = lrow[AGG_N] - rs0;
    int cnt = min(cnt_raw, AGG_CAP);

    int wave = t >> 6, lane = t & 63;
    // async staging: wave-uniform LDS base + lane*16 dest, per-lane global src.
    // chunks of 256 entries (1KB/wave-instr); overreads past cnt are masked later.
    for (int c = wave; c * 256 < cnt; c += 4) {
        const int* gsrc = csr_src + rs0 + c * 256 + lane * 4;
        __builtin_amdgcn_global_load_lds(
            (const __attribute__((address_space(1))) unsigned int*)gsrc,
            (__attribute__((address_space(3))) unsigned int*)&lcsr[c * 256],
            16, 0, 0);
    }
    asm volatile("s_waitcnt vmcnt(0)" ::: "memory");
    __syncthreads();

    int ns = lane >> 4, ep = (lane >> 1) & 7, fp = lane & 1;
    const __half2 h2one = __floats2half2_rn(1.f, 1.f);
    const __half2 h2zero = __floats2half2_rn(0.f, 0.f);

    if (cnt_raw <= AGG_CAP) {
        uint4 AvS, Av0, Av1, Av2; int Ars, Are;
        uint4 BvS, Bv0, Bv1, Bv2; int Brs, Bre;

#define AGG_ISSUE(P, vS, v0, v1, v2, rs_, re_)                                  \
        do {                                                                    \
            int nl_ = (P) * 16 + wave * 4 + ns;                                 \
            int node_ = nb + nl_;                                               \
            bool valid_ = node_ < N_NODES;                                      \
            int safe_ = valid_ ? node_ : (N_NODES - 1);                         \
            rs_ = valid_ ? lrow[nl_] : 0;                                       \
            re_ = valid_ ? lrow[nl_ + 1] : 0;                                   \
            int b_ = max(rs_ - rs0, 0) + ep;                                    \
            int se0_ = lcsr[min(b_,      AGG_CAP - 1)];                         \
            int se1_ = lcsr[min(b_ + 8,  AGG_CAP - 1)];                         \
            int se2_ = lcsr[min(b_ + 16, AGG_CAP - 1)];                         \
            se0_ = (rs_ + ep      < re_) ? se0_ : safe_;                        \
            se1_ = (rs_ + ep + 8  < re_) ? se1_ : safe_;                        \
            se2_ = (rs_ + ep + 16 < re_) ? se2_ : safe_;                        \
            vS = *(const uint4*)(tsl + (size_t)safe_ * 16 + fp * 8);            \
            v0 = *(const uint4*)(tsl + (size_t)se0_ * 16 + fp * 8);             \
            v1 = *(const uint4*)(tsl + (size_t)se1_ * 16 + fp * 8);             \
            v2 = *(const uint4*)(tsl + (size_t)se2_ * 16 + fp * 8);             \
        } while (0)

#define AGG_CONSUME(P, vS, v0, v1, v2, rs_, re_)                                \
        do {                                                                    \
            int nl_ = (P) * 16 + wave * 4 + ns;                                 \
            int node_ = nb + nl_;                                               \
            bool valid_ = node_ < N_NODES;                                      \
            __half2 mS_ = (valid_ && ep == 0) ? h2one : h2zero;                 \
            __half2 m0_ = (rs_ + ep      < re_) ? h2one : h2zero;               \
            __half2 m1_ = (rs_ + ep + 8  < re_) ? h2one : h2zero;               \
            __half2 m2_ = (rs_ + ep + 16 < re_) ? h2one : h2zero;               \
            __half2 a0_ = __hmul2(u2h2(vS.x), mS_);                             \
            __half2 a1_ = __hmul2(u2h2(vS.y), mS_);                             \
            __half2 a2_ = __hmul2(u2h2(vS.z), mS_);                             \
            __half2 a3_ = __hmul2(u2h2(vS.w), mS_);                             \
            a0_ = __hfma2(u2h2(v0.x), m0_, a0_);                                \
            a1_ = __hfma2(u2h2(v0.y), m0_, a1_);                                \
            a2_ = __hfma2(u2h2(v0.z), m0_, a2_);                                \
            a3_ = __hfma2(u2h2(v0.w), m0_, a3_);                                \
            a0_ = __hfma2(u2h2(v1.x), m1_, a0_);                                \
            a1_ = __hfma2(u2h2(v1.y), m1_, a1_);                                \
            a2_ = __hfma2(u2h2(v1.z), m1_, a2_);                                \
            a3_ = __hfma2(u2h2(v1.w), m1_, a3_);                                \
            a0_ = __hfma2(u2h2(v2.x), m2_, a0_);                                \
            a1_ = __hfma2(u2h2(v2.y), m2_, a1_);                                \
            a2_ = __hfma2(u2h2(v2.z), m2_, a2_);                                \
            a3_ = __hfma2(u2h2(v2.w), m2_, a3_);                                \
            if (__builtin_expect(__any(re_ - rs_ > 24), 0)) {                   \
                for (int q_ = rs_ + 24 + ep; q_ < re_; q_ += 8) {               \
                    int se_ = lcsr[q_ - rs0];                                   \
                    uint4 v_ = *(const uint4*)(tsl + (size_t)se_ * 16 + fp * 8);\
                    a0_ = __hadd2(a0_, u2h2(v_.x));                             \
                    a1_ = __hadd2(a1_, u2h2(v_.y));                             \
                    a2_ = __hadd2(a2_, u2h2(v_.z));                             \
                    a3_ = __hadd2(a3_, u2h2(v_.w));                             \
                }                                                               \
            }                                                                   \
            a0_ = __hadd2(a0_, u2h2(dppu<0x4E>(h22u(a0_))));                    \
            a1_ = __hadd2(a1_, u2h2(dppu<0x4E>(h22u(a1_))));                    \
            a2_ = __hadd2(a2_, u2h2(dppu<0x4E>(h22u(a2_))));                    \
            a3_ = __hadd2(a3_, u2h2(dppu<0x4E>(h22u(a3_))));                    \
            a0_ = __hadd2(a0_, u2h2(dppu<0x124>(h22u(a0_))));                   \
            a1_ = __hadd2(a1_, u2h2(dppu<0x124>(h22u(a1_))));                   \
            a2_ = __hadd2(a2_, u2h2(dppu<0x124>(h22u(a2_))));                   \
            a3_ = __hadd2(a3_, u2h2(dppu<0x124>(h22u(a3_))));                   \
            a0_ = __hadd2(a0_, u2h2(dppu<0x128>(h22u(a0_))));                   \
            a1_ = __hadd2(a1_, u2h2(dppu<0x128>(h22u(a1_))));                   \
            a2_ = __hadd2(a2_, u2h2(dppu<0x128>(h22u(a2_))));                   \
            a3_ = __hadd2(a3_, u2h2(dppu<0x128>(h22u(a3_))));                   \
            if (valid_ && ep == 0) {                                            \
                float di_ = rsqrtf((float)(re_ - rs_ + 1));                     \
                const float* bb_ = bsf + s * 16 + fp * 8;                       \
                float f_[8];                                                    \
                f_[0] = __low2float(a0_); f_[1] = __high2float(a0_);            \
                f_[2] = __low2float(a1_); f_[3] = __high2float(a1_);            \
                f_[4] = __low2float(a2_); f_[5] = __high2float(a2_);            \
                f_[6] = __low2float(a3_); f_[7] = __high2float(a3_);            \
                _Pragma("unroll")                                               \
                for (int j_ = 0; j_ < 8; j_++)                                  \
                    f_[j_] = fmaxf(di_ * f_[j_] + bb_[j_], 0.f);                \
                uint4 pv_;                                                      \
                pv_.x = h22u(__floats2half2_rn(f_[0], f_[1]));                  \
                pv_.y = h22u(__floats2half2_rn(f_[2], f_[3]));                  \
                pv_.z = h22u(__floats2half2_rn(f_[4], f_[5]));                  \
                pv_.w = h22u(__floats2half2_rn(f_[6], f_[7]));                  \
                *(uint4*)(h + (size_t)node_ * 64 + s * 16 + fp * 8) = pv_;      \
            }                                                                   \
        } while (0)

        AGG_ISSUE(0, AvS, Av0, Av1, Av2, Ars, Are);
        AGG_ISSUE(1, BvS, Bv0, Bv1, Bv2, Brs, Bre);
        AGG_CONSUME(0, AvS, Av0, Av1, Av2, Ars, Are);
        AGG_ISSUE(2, AvS, Av0, Av1, Av2, Ars, Are);
        AGG_CONSUME(1, BvS, Bv0, Bv1, Bv2, Brs, Bre);
        AGG_ISSUE(3, BvS, Bv0, Bv1, Bv2, Brs, Bre);
        AGG_CONSUME(2, AvS, Av0, Av1, Av2, Ars, Are);
        AGG_ISSUE(4, AvS, Av0, Av1, Av2, Ars, Are);
        AGG_CONSUME(3, BvS, Bv0, Bv1, Bv2, Brs, Bre);
        AGG_ISSUE(5, BvS, Bv0, Bv1, Bv2, Brs, Bre);
        AGG_CONSUME(4, AvS, Av0, Av1, Av2, Ars, Are);
        AGG_ISSUE(6, AvS, Av0, Av1, Av2, Ars, Are);
        AGG_CONSUME(5, BvS, Bv0, Bv1, Bv2, Brs, Bre);
        AGG_ISSUE(7, BvS, Bv0, Bv1, Bv2, Brs, Bre);
        AGG_CONSUME(6, AvS, Av0, Av1, Av2, Ars, Are);
        AGG_CONSUME(7, BvS, Bv0, Bv1, Bv2, Brs, Bre);
#undef AGG_ISSUE
#undef AGG_CONSUME
    } else {
        // slow path: staged-LDS overflow (block-uniform, essentially never taken)
#pragma unroll
        for (int pass = 0; pass < AGG_N / 16; pass++) {
            int nl = pass * 16 + wave * 4 + ns;
            int node = nb + nl;
            bool valid = node < N_NODES;
            int rs = valid ? lrow[nl] : 0;
            int re = valid ? lrow[nl + 1] : 0;
            __half2 a2[4];
#pragma unroll
            for (int r = 0; r < 4; r++) a2[r] = h2zero;
            if (valid && ep == 0) {
                uint4 v = *(const uint4*)(tsl + (size_t)node * 16 + fp * 8);
                a2[0] = __hadd2(a2[0], u2h2(v.x));
                a2[1] = __hadd2(a2[1], u2h2(v.y));
                a2[2] = __hadd2(a2[2], u2h2(v.z));
                a2[3] = __hadd2(a2[3], u2h2(v.w));
            }
            for (int base = rs; base + ep < re; base += 8) {
                int idx = base + ep - rs0;
                int se = (idx < AGG_CAP) ? lcsr[idx] : csr_src[base + ep];
                uint4 v = *(const uint4*)(tsl + (size_t)se * 16 + fp * 8);
                a2[0] = __hadd2(a2[0], u2h2(v.x));
                a2[1] = __hadd2(a2[1], u2h2(v.y));
                a2[2] = __hadd2(a2[2], u2h2(v.z));
                a2[3] = __hadd2(a2[3], u2h2(v.w));
            }
#pragma unroll
            for (int st = 2; st <= 8; st <<= 1) {
#pragma unroll
                for (int r = 0; r < 4; r++)
                    a2[r] = __hadd2(a2[r], u2h2(__shfl_xor(h22u(a2[r]), st)));
            }
            if (valid && ep == 0) {
                float di = rsqrtf((float)(re - rs + 1));
                const float* bb = bsf + s * 16 + fp * 8;
                float a[8];
#pragma unroll
                for (int r = 0; r < 4; r++) {
                    a[2 * r]     = __low2float(a2[r]);
                    a[2 * r + 1] = __high2float(a2[r]);
                }
#pragma unroll
                for (int j = 0; j < 8; j++) a[j] = fmaxf(di * a[j] + bb[j], 0.f);
                uint4 pv;
                pv.x = h22u(__floats2half2_rn(a[0], a[1]));
                pv.y = h22u(__floats2half2_rn(a[2], a[3]));
                pv.z = h22u(__floats2half2_rn(a[4], a[5]));
                pv.w = h22u(__floats2half2_rn(a[6], a[7]));
                *(uint4*)(h + (size_t)node * 64 + s * 16 + fp * 8) = pv;
            }
        }
    }
}

// ---------- final: out = out_acc + h7 @ lwB7 + lin_b ----------
__global__ __launch_bounds__(256) void jk_final_kernel(const __half* __restrict__ h,
                                                       const unsigned short* __restrict__ wJ,
                                                       const float* __restrict__ out_acc,
                                                       const void* __restrict__ lin_b,
                                                       const int* __restrict__ flags,
                                                       void* __restrict__ d_out) {
    bool f32 = flags[0] != 0;
    int wave = threadIdx.x >> 6, lane = threadIdx.x & 63;
    int quad = lane >> 4, m = lane & 15;
    int nb = blockIdx.x * 64 + wave * 16;
    int ra = nb + m;
    if (ra > N_NODES - 1) ra = N_NODES - 1;
    const short* hrow = (const short*)(h + (size_t)ra * 64) + quad * 8;
    short8 a0 = *(const short8*)(hrow);
    short8 a1 = *(const short8*)(hrow + 32);
#pragma unroll
    for (int ct = 0; ct < 3; ct++) {
        float4v j = (float4v){0.f, 0.f, 0.f, 0.f};
        short8 b0 = *(const short8*)(wJ + ((ct * 2 + 0) * 64 + lane) * 8);
        short8 b1 = *(const short8*)(wJ + ((ct * 2 + 1) * 64 + lane) * 8);
        j = __builtin_amdgcn_mfma_f32_16x16x32_f16(
            __builtin_bit_cast(half8, a0), __builtin_bit_cast(half8, b0), j, 0, 0, 0);
        j = __builtin_amdgcn_mfma_f32_16x16x32_f16(
            __builtin_bit_cast(half8, a1), __builtin_bit_cast(half8, b1), j, 0, 0, 0);
        int col = ct * 16 + m;
        if (col < OUT_DIM) {
            float lb = ldext(lin_b, f32, col);
#pragma unroll
            for (int r = 0; r < 4; r++) {
                int rw = nb + quad * 4 + r;
                if (rw < N_NODES) {
                    float v = out_acc[(size_t)rw * OUT_DIM + col] + j[r] + lb;
                    if (f32) ((float*)d_out)[(size_t)rw * OUT_DIM + col] = v;
                    else ((__hip_bfloat16*)d_out)[(size_t)rw * OUT_DIM + col] = __float2bfloat16(v);
                }
            }
        }
    }
}

extern "C" void kernel_launch(void* const* d_in, const int* in_sizes, int n_in,
                              void* d_out, int out_size, void* d_ws, size_t ws_size,
                              hipStream_t stream) {
    const void* x     = d_in[0];
    const void* W0    = d_in[1];
    const void* Ws    = d_in[2];
    const void* bs    = d_in[3];
    const void* lin_w = d_in[4];
    const void* lin_b = d_in[5];
    const void* ei    = d_in[6];

    size_t off = 0;
    auto alloc = [&](size_t bytes) -> void* {
        void* p = (char*)d_ws + off;
        off += (bytes + 511) & ~(size_t)511;
        return p;
    };
    int*   flags   = (int*)alloc(512);
    float* dis     = (float*)alloc((size_t)(N_NODES + 64) * 4);
    int*   deg     = (int*)alloc((size_t)N_NODES * 4);
    int*   row     = (int*)alloc((size_t)(N_NODES + 1) * 4);
    int*   bsums   = (int*)alloc(128 * 4);
    int*   gcur    = (int*)alloc((size_t)NBUK * 4);
    int*   fifo    = (int*)alloc((size_t)NBUK * BUK_CAP * 4);   // 9.4 MB
    int*   csr_src = (int*)alloc((size_t)N_EDGES * 4);
    __half* t0s = (__half*)alloc((size_t)4 * T0SL4 * 2);
    __half* h   = (__half*)alloc((size_t)(N_NODES + 32) * HID * 2);
    float* out_acc = (float*)alloc((size_t)N_NODES * OUT_DIM * 4);
    float* bsf     = (float*)alloc((size_t)LAYERS * HID * 4);
    unsigned short* wpack = (unsigned short*)alloc((size_t)61440 * 2);

    const int nblkN  = (N_NODES + 255) / 256;
    const int nblkS1 = (N_EDGES + S1_EPB - 1) / S1_EPB;   // 782
    const int nblkMM = (N_NODES + 63) / 64;               // 1563
    const int nblkAG = ((N_NODES + AGG_N - 1) / AGG_N) * 4;  // 782*4 = 3128

    detect_kernel<<<1, 64, 0, stream>>>(x, ei, flags, gcur);
    pack_params_kernel<<<80, 256, 0, stream>>>(bs, lin_w, W0, Ws, flags, bsf, wpack);
    bucket1_kernel<<<nblkS1, 256, 0, stream>>>(ei, flags, gcur, fifo);
    deg_fifo_kernel<<<NBUK, 256, 0, stream>>>(gcur, fifo, deg, dis);
    scan1_kernel<<<SCAN_NB, 256, 0, stream>>>(deg, row, bsums);
    scan2_kernel<<<1, 128, 0, stream>>>(bsums);
    scan3_kernel<<<nblkN, 256, 0, stream>>>(row, bsums);
    bucket2_kernel<<<NBUK, 256, 0, stream>>>(gcur, fifo, row, csr_src);

    const unsigned short* wJ0 = wpack + 36864;
    for (int l = 0; l < LAYERS; l++) {
        if (l == 0) {
            mm_mfma_kernel<4, 0, true><<<nblkMM, 256, 0, stream>>>(
                x, x, flags, wpack, nullptr, dis, t0s, nullptr);
        } else if (l == 1) {
            mm_mfma_kernel<2, 1, false><<<nblkMM, 256, 0, stream>>>(
                h, h, flags, wpack + 8192, wJ0, dis, t0s, out_acc);
        } else {
            mm_mfma_kernel<2, 2, false><<<nblkMM, 256, 0, stream>>>(
                h, h, flags, wpack + 8192 + (size_t)(l - 1) * 4096,
                wJ0 + (size_t)(l - 1) * 3072, dis, t0s, out_acc);
        }
        agg_kernel<<<nblkAG, 256, 0, stream>>>(t0s, row, csr_src,
                                               bsf + (size_t)l * HID, h);
    }
    jk_final_kernel<<<nblkMM, 256, 0, stream>>>(h, wJ0 + (size_t)7 * 3072, out_acc,
                                                lin_b, flags, d_out);
}

// Round 4
// 628.165 us; speedup vs baseline: 1.1404x; 1.0086x over previous
//
#include <hip/hip_runtime.h>
#include <hip/hip_bf16.h>
#include <hip/hip_fp16.h>

#define N_NODES 100000
#define N_EDGES 1600000
#define HID     64
#define LAYERS  8
#define OUT_DIM 40
#define SCAN_NB 98   // ceil(100000/1024)
#define T0SL4   ((size_t)(N_NODES + 32) * 16)   // elements per t0 quarter-slice (16 feats)
#define NBUK    196      // ceil(100000/512) buckets of 512 nodes
#define BUK_CAP 12000    // avg 8163/bucket -> huge sigma headroom
#define S1_EPB  2048     // edges per bucket1 block (256 thr x 8)
#define AGG_N   128      // nodes per agg block
#define AGG_CAP 3072     // staged csr entries (mean 2048, +22 sigma), 12KB LDS

typedef __attribute__((ext_vector_type(8))) short short8;
typedef __attribute__((ext_vector_type(8))) _Float16 half8;
typedef __attribute__((ext_vector_type(4))) float float4v;

// ---------- runtime environment hedges ----------
// flags[0] = 1 if feature inputs are float32 (else bf16)
// flags[1] = 1 if edge_index is int64 (else int32)
__device__ inline float ldext(const void* p, bool f32, size_t i) {
    return f32 ? ((const float*)p)[i]
               : __bfloat162float(((const __hip_bfloat16*)p)[i]);
}
__device__ inline int load_edge(const void* raw, bool is64, long long idx) {
    return is64 ? (int)((const long long*)raw)[idx] : ((const int*)raw)[idx];
}
__device__ inline unsigned pack_bf16x2(float lo, float hi) {
    union { __hip_bfloat16 b; unsigned short u; } a, b;
    a.b = __float2bfloat16(lo);
    b.b = __float2bfloat16(hi);
    return ((unsigned)b.u << 16) | a.u;
}
__device__ inline unsigned short bf16bits(float v) {
    union { __hip_bfloat16 b; unsigned short u; } a;
    a.b = __float2bfloat16(v);
    return a.u;
}
__device__ inline unsigned short f16bits(float v) {
    union { __half h; unsigned short u; } a;
    a.h = __float2half_rn(v);
    return a.u;
}
__device__ inline __half2 u2h2(unsigned u) {
    union { unsigned u; __half2 h; } x; x.u = u; return x.h;
}
__device__ inline unsigned h22u(__half2 h) {
    union { unsigned u; __half2 h; } x; x.h = h; return x.u;
}

// DPP lane-rotation move (VALU pipe; replaces ds-pipe shuffles in the ep-reduce).
// 0x4E = quad_perm[2,3,0,1] (xor 2); 0x124 = row_ror:4; 0x128 = row_ror:8.
// Rotations within a row of 16 are valid for a commutative sum over lane bits 1..3
// and preserve bit 0 (fp parity).
template <int CTRL>
__device__ inline unsigned dppu(unsigned v) {
    return (unsigned)__builtin_amdgcn_update_dpp((int)v, (int)v, CTRL, 0xF, 0xF, false);
}

// also zeroes gcur (fused former zero_int_kernel)
__global__ void detect_kernel(const void* x, const void* ei, int* flags, int* gcur) {
    int t = threadIdx.x;  // 64 threads
    for (int i = t; i < NBUK; i += 64) gcur[i] = 0;
    float v = fabsf(__bfloat162float(((const __hip_bfloat16*)x)[t]));
    bool inband = (v >= 0.00390625f && v <= 16.0f);
    unsigned long long m = __ballot(inband);
    if (t == 0) {
        flags[0] = (__popcll(m) < 48) ? 1 : 0;  // fp32 misread as bf16 -> ~33/64 in band
        const int* e32 = (const int*)ei;
        flags[1] = ((e32[1] | e32[3] | e32[5] | e32[7]) == 0) ? 1 : 0;
    }
}

// pack: bias (fp32); W0 as bf16 MFMA B-frags; W1..7 and lwB as f16 MFMA B-frags.
__global__ __launch_bounds__(256) void pack_params_kernel(const void* bs, const void* lin_w,
                                                          const void* W0, const void* Ws,
                                                          const int* __restrict__ flags,
                                                          float* __restrict__ bsf,
                                                          unsigned short* __restrict__ wpack) {
    bool f32 = flags[0] != 0;
    int gid = blockIdx.x * 256 + threadIdx.x;
    int stride = gridDim.x * 256;
    for (int idx = gid; idx < LAYERS * HID; idx += stride) bsf[idx] = ldext(bs, f32, idx);
    // layer 0 W: K=128 (KS=4), 8192 elements, bf16 (A = x is bf16)
    for (int idx = gid; idx < 8192; idx += stride) {
        int j = idx & 7, lane = (idx >> 3) & 63, rest = idx >> 9;
        int ks = rest & 3, ct = rest >> 2;
        int quad = lane >> 4, m = lane & 15;
        wpack[idx] = bf16bits(ldext(W0, f32, (size_t)(ks * 32 + quad * 8 + j) * 64 + ct * 16 + m));
    }
    // layers 1..7 W: K=64 (KS=2), 4096 each, f16 (A = h is f16)
    for (int idx = gid; idx < 7 * 4096; idx += stride) {
        int l = idx >> 12, r = idx & 4095;
        int j = r & 7, lane = (r >> 3) & 63, rest = r >> 9;
        int ks = rest & 1, ct = rest >> 1;
        int quad = lane >> 4, m = lane & 15;
        wpack[8192 + idx] = f16bits(
            ldext(Ws, f32, (size_t)l * 4096 + (size_t)(ks * 32 + quad * 8 + j) * 64 + ct * 16 + m));
    }
    // lwB: 8 layers x 3072 (3 ct x 2 ks x 64 lanes x 8), f16
    for (int idx = gid; idx < LAYERS * 3072; idx += stride) {
        int l = idx / 3072, r = idx % 3072;
        int j = r & 7, lane = (r >> 3) & 63, rest = r >> 9;
        int ks = rest & 1, ct = rest >> 1;
        int quad = lane >> 4, m = lane & 15;
        int col = ct * 16 + m;
        int k = l * 64 + ks * 32 + quad * 8 + j;
        wpack[36864 + idx] = (col < OUT_DIM)
            ? f16bits(ldext(lin_w, f32, (size_t)k * OUT_DIM + col)) : (unsigned short)0;
    }
}

// ---------- phase 1: LDS counting-sort append into per-bucket FIFOs ----------
__global__ __launch_bounds__(256) void bucket1_kernel(const void* ei_raw, const int* __restrict__ flags,
                                                      int* __restrict__ gcur, int* __restrict__ fifo) {
    __shared__ int lhist[NBUK];
    __shared__ int lbase[NBUK];
    bool is64 = flags[1] != 0;
    int t = threadIdx.x;
    for (int i = t; i < NBUK; i += 256) lhist[i] = 0;
    __syncthreads();
    int e0 = blockIdx.x * S1_EPB;
    int rec[8], bk[8], loff[8];
#pragma unroll
    for (int j = 0; j < 8; j++) {
        int e = e0 + j * 256 + t;
        bk[j] = -1;
        if (e < N_EDGES) {
            int s = load_edge(ei_raw, is64, e);
            int d = load_edge(ei_raw, is64, (long long)N_EDGES + e);
            int b = d >> 9;
            bk[j] = b;
            rec[j] = ((d & 511) << 17) | s;
            loff[j] = atomicAdd(&lhist[b], 1);
        }
    }
    __syncthreads();
    for (int i = t; i < NBUK; i += 256)
        lbase[i] = (lhist[i] > 0) ? atomicAdd(&gcur[i], lhist[i]) : 0;
    __syncthreads();
#pragma unroll
    for (int j = 0; j < 8; j++) {
        if (bk[j] >= 0) {
            int idx = lbase[bk[j]] + loff[j];
            if (idx < BUK_CAP) fifo[bk[j] * BUK_CAP + idx] = rec[j];
        }
    }
}

// ---------- degree + dis from FIFO (LDS counters; fused former calc_dis) ----------
__global__ __launch_bounds__(256) void deg_fifo_kernel(const int* __restrict__ gcur,
                                                       const int* __restrict__ fifo,
                                                       int* __restrict__ deg,
                                                       float* __restrict__ dis) {
    __shared__ int ldeg[512];
    int b = blockIdx.x, t = threadIdx.x;
    ldeg[t] = 0;
    ldeg[t + 256] = 0;
    __syncthreads();
    int cnt = min(gcur[b], BUK_CAP);
    for (int i = t; i < cnt; i += 256)
        atomicAdd(&ldeg[fifo[b * BUK_CAP + i] >> 17], 1);
    __syncthreads();
    int n0 = b * 512 + t;
    if (n0 < N_NODES) {
        int d = ldeg[t];
        deg[n0] = d;
        dis[n0] = rsqrtf((float)(d + 1));  // +1 self-loop
    }
    if (n0 + 256 < N_NODES) {
        int d = ldeg[t + 256];
        deg[n0 + 256] = d;
        dis[n0 + 256] = rsqrtf((float)(d + 1));
    }
}

// exclusive scan of deg -> row (3-kernel, 1024 elems/block)
__global__ __launch_bounds__(256) void scan1_kernel(const int* __restrict__ deg, int* __restrict__ row,
                                                    int* __restrict__ bsums) {
    __shared__ int sd[256];
    int t = threadIdx.x;
    int base = blockIdx.x * 1024 + t * 4;
    int v[4];
#pragma unroll
    for (int j = 0; j < 4; j++) {
        int idx = base + j;
        v[j] = (idx < N_NODES) ? deg[idx] : 0;
    }
    int s4 = v[0] + v[1] + v[2] + v[3];
    sd[t] = s4;
    __syncthreads();
    for (int off = 1; off < 256; off <<= 1) {
        int x = (t >= off) ? sd[t - off] : 0;
        __syncthreads();
        sd[t] += x;
        __syncthreads();
    }
    int run = sd[t] - s4;  // exclusive
#pragma unroll
    for (int j = 0; j < 4; j++) {
        int idx = base + j;
        if (idx < N_NODES) row[idx] = run;
        run += v[j];
    }
    if (t == 255) bsums[blockIdx.x] = sd[255];
}

__global__ void scan2_kernel(int* bsums) {
    __shared__ int sd[128];
    int t = threadIdx.x;
    int v = (t < SCAN_NB) ? bsums[t] : 0;
    sd[t] = v;
    __syncthreads();
    for (int off = 1; off < 128; off <<= 1) {
        int x = (t >= off) ? sd[t - off] : 0;
        __syncthreads();
        sd[t] += x;
        __syncthreads();
    }
    if (t < SCAN_NB) bsums[t] = sd[t] - v;  // exclusive block offsets
}

__global__ __launch_bounds__(256) void scan3_kernel(int* __restrict__ row, const int* __restrict__ bsums) {
    int i = blockIdx.x * 256 + threadIdx.x;
    if (i < N_NODES) row[i] += bsums[i >> 10];
    if (i == 0) row[N_NODES] = N_EDGES;
}

// ---------- phase 2: per-bucket scatter to final CSR with LDS cursors ----------
__global__ __launch_bounds__(256) void bucket2_kernel(const int* __restrict__ gcur,
                                                      const int* __restrict__ fifo,
                                                      const int* __restrict__ row,
                                                      int* __restrict__ csr_src) {
    __shared__ int lcur[512];
    int b = blockIdx.x, t = threadIdx.x;
    int n0 = b * 512 + t;
    lcur[t] = row[min(n0, N_NODES)];
    lcur[t + 256] = row[min(n0 + 256, N_NODES)];
    __syncthreads();
    int cnt = min(gcur[b], BUK_CAP);
    for (int i = t; i < cnt; i += 256) {
        int r = fifo[b * BUK_CAP + i];
        int pos = atomicAdd(&lcur[r >> 17], 1);
        csr_src[pos] = r & 0x1FFFF;
    }
}

// ---------- MFMA matmul: t0s (f16, 4 quarter-slices, dis-prescaled) = dis .* (h @ W) ----------
// ABF16: A/wW are bf16 (layer 0, A = x, converted in-register if fp32); else f16 (A = h).
// JK: 0 = none, 1 = out_acc = h @ lwB, 2 = out_acc += h @ lwB (exclusive per node)
template <int KS, int JK, bool ABF16>
__global__ __launch_bounds__(256) void mm_mfma_kernel(const void* __restrict__ h0,
                                                      const void* __restrict__ h1,
                                                      const int* __restrict__ flags,
                                                      const unsigned short* __restrict__ wW,
                                                      const unsigned short* __restrict__ wJ,
                                                      const float* __restrict__ dis,
                                                      __half* __restrict__ t0s,
                                                      float* __restrict__ out_acc) {
    constexpr int K = KS * 32;
    int wave = threadIdx.x >> 6, lane = threadIdx.x & 63;
    int quad = lane >> 4, m = lane & 15;
    int nb = blockIdx.x * 64 + wave * 16;
    int ra = nb + m;
    if (ra > N_NODES - 1) ra = N_NODES - 1;  // clamp tail (avoids OOB read)
    short8 a[KS];
    if constexpr (ABF16) {
        if (flags[0]) {
            // fp32 input: load floats, convert to bf16 in-register (replaces convert_x pass)
            const float* xr = (const float*)h1 + (size_t)ra * K + quad * 8;
#pragma unroll
            for (int ks = 0; ks < KS; ks++) {
                float4 f0 = *(const float4*)(xr + ks * 32);
                float4 f1 = *(const float4*)(xr + ks * 32 + 4);
                short8 v;
                v[0] = (short)bf16bits(f0.x); v[1] = (short)bf16bits(f0.y);
                v[2] = (short)bf16bits(f0.z); v[3] = (short)bf16bits(f0.w);
                v[4] = (short)bf16bits(f1.x); v[5] = (short)bf16bits(f1.y);
                v[6] = (short)bf16bits(f1.z); v[7] = (short)bf16bits(f1.w);
                a[ks] = v;
            }
        } else {
            const short* hrow = (const short*)h0 + (size_t)ra * K + quad * 8;
#pragma unroll
            for (int ks = 0; ks < KS; ks++) a[ks] = *(const short8*)(hrow + ks * 32);
        }
    } else {
        const short* hrow = (const short*)h0 + (size_t)ra * K + quad * 8;
#pragma unroll
        for (int ks = 0; ks < KS; ks++) a[ks] = *(const short8*)(hrow + ks * 32);
    }
    float dr[4];
#pragma unroll
    for (int r = 0; r < 4; r++) {
        int rw = nb + quad * 4 + r;
        dr[r] = dis[rw < N_NODES ? rw : (N_NODES - 1)];
    }
#pragma unroll
    for (int ct = 0; ct < 4; ct++) {
        float4v acc = (float4v){0.f, 0.f, 0.f, 0.f};
#pragma unroll
        for (int ks = 0; ks < KS; ks++) {
            short8 b = *(const short8*)(wW + ((ct * KS + ks) * 64 + lane) * 8);
            if constexpr (ABF16)
                acc = __builtin_amdgcn_mfma_f32_16x16x32_bf16(a[ks], b, acc, 0, 0, 0);
            else
                acc = __builtin_amdgcn_mfma_f32_16x16x32_f16(
                    __builtin_bit_cast(half8, a[ks]), __builtin_bit_cast(half8, b), acc, 0, 0, 0);
        }
        // quarter-slice ct holds features ct*16..ct*16+15
#pragma unroll
        for (int r = 0; r < 4; r++) {
            t0s[(size_t)ct * T0SL4 + (size_t)(nb + quad * 4 + r) * 16 + m] =
                __float2half(acc[r] * dr[r]);
        }
    }
    if (JK) {
#pragma unroll
        for (int ct = 0; ct < 3; ct++) {
            float4v j = (float4v){0.f, 0.f, 0.f, 0.f};
#pragma unroll
            for (int ks = 0; ks < KS; ks++) {
                short8 b = *(const short8*)(wJ + ((ct * KS + ks) * 64 + lane) * 8);
                if constexpr (ABF16)
                    j = __builtin_amdgcn_mfma_f32_16x16x32_bf16(a[ks], b, j, 0, 0, 0);
                else
                    j = __builtin_amdgcn_mfma_f32_16x16x32_f16(
                        __builtin_bit_cast(half8, a[ks]), __builtin_bit_cast(half8, b), j, 0, 0, 0);
            }
            int col = ct * 16 + m;
            if (col < OUT_DIM) {
#pragma unroll
                for (int r = 0; r < 4; r++) {
                    int rw = nb + quad * 4 + r;
                    if (rw < N_NODES) {
                        size_t o = (size_t)rw * OUT_DIM + col;
                        if (JK == 1) out_acc[o] = j[r];
                        else out_acc[o] += j[r];
                    }
                }
            }
        }
    }
}

// ---------- aggregation: 4 XCD-affine quarter-slices, staged csr, 4 nodes/wave ----------
// R2 restructure (resubmit after infra failure):
//  * self-loop merged into gather round 0 (lane ep==0 fetches self; ep=1..7 fetch
//    edges rs..rs+6; rounds 1,2 cover rs+7..rs+22): 3 gathers/pass instead of 4;
//  * 3-deep software pipeline (states A,B,C) so each gather window is covered by
//    ~2 consumes of latency;
//  * lcsr staged at +4 ints so all round indices are in-range without clamps;
//  * ep-reduce via DPP rotations (VALU pipe); deg>23 tail behind __any guard.
__global__ __launch_bounds__(256, 6) void agg_kernel(const __half* __restrict__ t0s,
                                                     const int* __restrict__ row,
                                                     const int* __restrict__ csr_src,
                                                     const float* __restrict__ bsf,   // this layer, 64 f32
                                                     __half* __restrict__ h) {
    __shared__ int lrow[AGG_N + 1];
    __shared__ __align__(16) int lcsr[AGG_CAP + 32];
    int t = threadIdx.x;
    int s = blockIdx.x & 3;
    int nb = (blockIdx.x >> 2) * AGG_N;
    const __half* tsl = t0s + (size_t)s * T0SL4;

    for (int i = t; i <= AGG_N; i += 256) {
        int n = nb + i;
        lrow[i] = row[n > N_NODES ? N_NODES : n];
    }
    __syncthreads();
    int rs0 = lrow[0];
    int cnt_raw = lrow[AGG_N] - rs0;
    int cnt = min(cnt_raw, AGG_CAP);

    int wave = t >> 6, lane = t & 63;
    // async staging into lcsr[4..4+cnt): wave-uniform LDS base + lane*16 dest,
    // per-lane global src; chunks of 256 entries (1KB/wave-instr).
    for (int c = wave; c * 256 < cnt; c += 4) {
        const int* gsrc = csr_src + rs0 + c * 256 + lane * 4;
        __builtin_amdgcn_global_load_lds(
            (const __attribute__((address_space(1))) unsigned int*)gsrc,
            (__attribute__((address_space(3))) unsigned int*)&lcsr[4 + c * 256],
            16, 0, 0);
    }
    asm volatile("s_waitcnt vmcnt(0)" ::: "memory");
    __syncthreads();

    int ns = lane >> 4, ep = (lane >> 1) & 7, fp = lane & 1;
    const __half2 h2one = __floats2half2_rn(1.f, 1.f);
    const __half2 h2zero = __floats2half2_rn(0.f, 0.f);

    if (cnt_raw <= AGG_CAP) {
        uint4 Av0, Av1, Av2; int Ars, Are;
        uint4 Bv0, Bv1, Bv2; int Brs, Bre;
        uint4 Cv0, Cv1, Cv2; int Crs, Cre;

#define AGG_ISSUE(P, v0, v1, v2, rs_, re_)                                      \
        do {                                                                    \
            int nl_ = (P) * 16 + wave * 4 + ns;                                 \
            int node_ = nb + nl_;                                               \
            bool valid_ = node_ < N_NODES;                                      \
            int safe_ = valid_ ? node_ : (N_NODES - 1);                         \
            rs_ = valid_ ? lrow[nl_] : 0;                                       \
            re_ = valid_ ? lrow[nl_ + 1] : 0;                                   \
            int b_ = max(rs_ - rs0, 0) + ep;                                    \
            int se0_ = lcsr[b_ + 3];   /* edge rs+ep-1 */                       \
            int se1_ = lcsr[b_ + 11];  /* edge rs+ep+7 */                       \
            int se2_ = lcsr[b_ + 19];  /* edge rs+ep+15 */                      \
            se0_ = (ep == 0) ? safe_ : ((rs_ + ep - 1 < re_) ? se0_ : safe_);   \
            se1_ = (rs_ + ep + 7  < re_) ? se1_ : safe_;                        \
            se2_ = (rs_ + ep + 15 < re_) ? se2_ : safe_;                        \
            v0 = *(const uint4*)(tsl + (size_t)se0_ * 16 + fp * 8);             \
            v1 = *(const uint4*)(tsl + (size_t)se1_ * 16 + fp * 8);             \
            v2 = *(const uint4*)(tsl + (size_t)se2_ * 16 + fp * 8);             \
        } while (0)

#define AGG_CONSUME(P, v0, v1, v2, rs_, re_)                                    \
        do {                                                                    \
            int nl_ = (P) * 16 + wave * 4 + ns;                                 \
            int node_ = nb + nl_;                                               \
            bool valid_ = node_ < N_NODES;                                      \
            __half2 m0_ = ((ep == 0) ? valid_ : (rs_ + ep - 1 < re_))           \
                              ? h2one : h2zero;                                 \
            __half2 m1_ = (rs_ + ep + 7  < re_) ? h2one : h2zero;               \
            __half2 m2_ = (rs_ + ep + 15 < re_) ? h2one : h2zero;               \
            __half2 a0_ = __hmul2(u2h2(v0.x), m0_);                             \
            __half2 a1_ = __hmul2(u2h2(v0.y), m0_);                             \
            __half2 a2_ = __hmul2(u2h2(v0.z), m0_);                             \
            __half2 a3_ = __hmul2(u2h2(v0.w), m0_);                             \
            a0_ = __hfma2(u2h2(v1.x), m1_, a0_);                                \
            a1_ = __hfma2(u2h2(v1.y), m1_, a1_);                                \
            a2_ = __hfma2(u2h2(v1.z), m1_, a2_);                                \
            a3_ = __hfma2(u2h2(v1.w), m1_, a3_);                                \
            a0_ = __hfma2(u2h2(v2.x), m2_, a0_);                                \
            a1_ = __hfma2(u2h2(v2.y), m2_, a1_);                                \
            a2_ = __hfma2(u2h2(v2.z), m2_, a2_);                                \
            a3_ = __hfma2(u2h2(v2.w), m2_, a3_);                                \
            if (__builtin_expect(__any(re_ - rs_ > 23), 0)) {                   \
                for (int q_ = rs_ + 23 + ep; q_ < re_; q_ += 8) {               \
                    int se_ = lcsr[4 + q_ - rs0];                               \
                    uint4 v_ = *(const uint4*)(tsl + (size_t)se_ * 16 + fp * 8);\
                    a0_ = __hadd2(a0_, u2h2(v_.x));                             \
                    a1_ = __hadd2(a1_, u2h2(v_.y));                             \
                    a2_ = __hadd2(a2_, u2h2(v_.z));                             \
                    a3_ = __hadd2(a3_, u2h2(v_.w));                             \
                }                                                               \
            }                                                                   \
            a0_ = __hadd2(a0_, u2h2(dppu<0x4E>(h22u(a0_))));                    \
            a1_ = __hadd2(a1_, u2h2(dppu<0x4E>(h22u(a1_))));                    \
            a2_ = __hadd2(a2_, u2h2(dppu<0x4E>(h22u(a2_))));                    \
            a3_ = __hadd2(a3_, u2h2(dppu<0x4E>(h22u(a3_))));                    \
            a0_ = __hadd2(a0_, u2h2(dppu<0x124>(h22u(a0_))));                   \
            a1_ = __hadd2(a1_, u2h2(dppu<0x124>(h22u(a1_))));                   \
            a2_ = __hadd2(a2_, u2h2(dppu<0x124>(h22u(a2_))));                   \
            a3_ = __hadd2(a3_, u2h2(dppu<0x124>(h22u(a3_))));                   \
            a0_ = __hadd2(a0_, u2h2(dppu<0x128>(h22u(a0_))));                   \
            a1_ = __hadd2(a1_, u2h2(dppu<0x128>(h22u(a1_))));                   \
            a2_ = __hadd2(a2_, u2h2(dppu<0x128>(h22u(a2_))));                   \
            a3_ = __hadd2(a3_, u2h2(dppu<0x128>(h22u(a3_))));                   \
            if (valid_ && ep == 0) {                                            \
                float di_ = rsqrtf((float)(re_ - rs_ + 1));                     \
                const float* bb_ = bsf + s * 16 + fp * 8;                       \
                float f_[8];                                                    \
                f_[0] = __low2float(a0_); f_[1] = __high2float(a0_);            \
                f_[2] = __low2float(a1_); f_[3] = __high2float(a1_);            \
                f_[4] = __low2float(a2_); f_[5] = __high2float(a2_);            \
                f_[6] = __low2float(a3_); f_[7] = __high2float(a3_);            \
                _Pragma("unroll")                                               \
                for (int j_ = 0; j_ < 8; j_++)                                  \
                    f_[j_] = fmaxf(di_ * f_[j_] + bb_[j_], 0.f);                \
                uint4 pv_;                                                      \
                pv_.x = h22u(__floats2half2_rn(f_[0], f_[1]));                  \
                pv_.y = h22u(__floats2half2_rn(f_[2], f_[3]));                  \
                pv_.z = h22u(__floats2half2_rn(f_[4], f_[5]));                  \
                pv_.w = h22u(__floats2half2_rn(f_[6], f_[7]));                  \
                *(uint4*)(h + (size_t)node_ * 64 + s * 16 + fp * 8) = pv_;      \
            }                                                                   \
        } while (0)

        AGG_ISSUE(0, Av0, Av1, Av2, Ars, Are);
        AGG_ISSUE(1, Bv0, Bv1, Bv2, Brs, Bre);
        AGG_ISSUE(2, Cv0, Cv1, Cv2, Crs, Cre);
        AGG_CONSUME(0, Av0, Av1, Av2, Ars, Are);
        AGG_ISSUE(3, Av0, Av1, Av2, Ars, Are);
        AGG_CONSUME(1, Bv0, Bv1, Bv2, Brs, Bre);
        AGG_ISSUE(4, Bv0, Bv1, Bv2, Brs, Bre);
        AGG_CONSUME(2, Cv0, Cv1, Cv2, Crs, Cre);
        AGG_ISSUE(5, Cv0, Cv1, Cv2, Crs, Cre);
        AGG_CONSUME(3, Av0, Av1, Av2, Ars, Are);
        AGG_ISSUE(6, Av0, Av1, Av2, Ars, Are);
        AGG_CONSUME(4, Bv0, Bv1, Bv2, Brs, Bre);
        AGG_ISSUE(7, Bv0, Bv1, Bv2, Brs, Bre);
        AGG_CONSUME(5, Cv0, Cv1, Cv2, Crs, Cre);
        AGG_CONSUME(6, Av0, Av1, Av2, Ars, Are);
        AGG_CONSUME(7, Bv0, Bv1, Bv2, Brs, Bre);
#undef AGG_ISSUE
#undef AGG_CONSUME
    } else {
        // slow path: staged-LDS overflow (block-uniform, essentially never taken)
#pragma unroll
        for (int pass = 0; pass < AGG_N / 16; pass++) {
            int nl = pass * 16 + wave * 4 + ns;
            int node = nb + nl;
            bool valid = node < N_NODES;
            int rs = valid ? lrow[nl] : 0;
            int re = valid ? lrow[nl + 1] : 0;
            __half2 a2[4];
#pragma unroll
            for (int r = 0; r < 4; r++) a2[r] = h2zero;
            if (valid && ep == 0) {
                uint4 v = *(const uint4*)(tsl + (size_t)node * 16 + fp * 8);
                a2[0] = __hadd2(a2[0], u2h2(v.x));
                a2[1] = __hadd2(a2[1], u2h2(v.y));
                a2[2] = __hadd2(a2[2], u2h2(v.z));
                a2[3] = __hadd2(a2[3], u2h2(v.w));
            }
            for (int base = rs; base + ep < re; base += 8) {
                int idx = base + ep - rs0;
                int se = (idx < AGG_CAP) ? lcsr[4 + idx] : csr_src[base + ep];
                uint4 v = *(const uint4*)(tsl + (size_t)se * 16 + fp * 8);
                a2[0] = __hadd2(a2[0], u2h2(v.x));
                a2[1] = __hadd2(a2[1], u2h2(v.y));
                a2[2] = __hadd2(a2[2], u2h2(v.z));
                a2[3] = __hadd2(a2[3], u2h2(v.w));
            }
#pragma unroll
            for (int st = 2; st <= 8; st <<= 1) {
#pragma unroll
                for (int r = 0; r < 4; r++)
                    a2[r] = __hadd2(a2[r], u2h2(__shfl_xor(h22u(a2[r]), st)));
            }
            if (valid && ep == 0) {
                float di = rsqrtf((float)(re - rs + 1));
                const float* bb = bsf + s * 16 + fp * 8;
                float a[8];
#pragma unroll
                for (int r = 0; r < 4; r++) {
                    a[2 * r]     = __low2float(a2[r]);
                    a[2 * r + 1] = __high2float(a2[r]);
                }
#pragma unroll
                for (int j = 0; j < 8; j++) a[j] = fmaxf(di * a[j] + bb[j], 0.f);
                uint4 pv;
                pv.x = h22u(__floats2half2_rn(a[0], a[1]));
                pv.y = h22u(__floats2half2_rn(a[2], a[3]));
                pv.z = h22u(__floats2half2_rn(a[4], a[5]));
                pv.w = h22u(__floats2half2_rn(a[6], a[7]));
                *(uint4*)(h + (size_t)node * 64 + s * 16 + fp * 8) = pv;
            }
        }
    }
}

// ---------- final: out = out_acc + h7 @ lwB7 + lin_b ----------
__global__ __launch_bounds__(256) void jk_final_kernel(const __half* __restrict__ h,
                                                       const unsigned short* __restrict__ wJ,
                                                       const float* __restrict__ out_acc,
                                                       const void* __restrict__ lin_b,
                                                       const int* __restrict__ flags,
                                                       void* __restrict__ d_out) {
    bool f32 = flags[0] != 0;
    int wave = threadIdx.x >> 6, lane = threadIdx.x & 63;
    int quad = lane >> 4, m = lane & 15;
    int nb = blockIdx.x * 64 + wave * 16;
    int ra = nb + m;
    if (ra > N_NODES - 1) ra = N_NODES - 1;
    const short* hrow = (const short*)(h + (size_t)ra * 64) + quad * 8;
    short8 a0 = *(const short8*)(hrow);
    short8 a1 = *(const short8*)(hrow + 32);
#pragma unroll
    for (int ct = 0; ct < 3; ct++) {
        float4v j = (float4v){0.f, 0.f, 0.f, 0.f};
        short8 b0 = *(const short8*)(wJ + ((ct * 2 + 0) * 64 + lane) * 8);
        short8 b1 = *(const short8*)(wJ + ((ct * 2 + 1) * 64 + lane) * 8);
        j = __builtin_amdgcn_mfma_f32_16x16x32_f16(
            __builtin_bit_cast(half8, a0), __builtin_bit_cast(half8, b0), j, 0, 0, 0);
        j = __builtin_amdgcn_mfma_f32_16x16x32_f16(
            __builtin_bit_cast(half8, a1), __builtin_bit_cast(half8, b1), j, 0, 0, 0);
        int col = ct * 16 + m;
        if (col < OUT_DIM) {
            float lb = ldext(lin_b, f32, col);
#pragma unroll
            for (int r = 0; r < 4; r++) {
                int rw = nb + quad * 4 + r;
                if (rw < N_NODES) {
                    float v = out_acc[(size_t)rw * OUT_DIM + col] + j[r] + lb;
                    if (f32) ((float*)d_out)[(size_t)rw * OUT_DIM + col] = v;
                    else ((__hip_bfloat16*)d_out)[(size_t)rw * OUT_DIM + col] = __float2bfloat16(v);
                }
            }
        }
    }
}

extern "C" void kernel_launch(void* const* d_in, const int* in_sizes, int n_in,
                              void* d_out, int out_size, void* d_ws, size_t ws_size,
                              hipStream_t stream) {
    const void* x     = d_in[0];
    const void* W0    = d_in[1];
    const void* Ws    = d_in[2];
    const void* bs    = d_in[3];
    const void* lin_w = d_in[4];
    const void* lin_b = d_in[5];
    const void* ei    = d_in[6];

    size_t off = 0;
    auto alloc = [&](size_t bytes) -> void* {
        void* p = (char*)d_ws + off;
        off += (bytes + 511) & ~(size_t)511;
        return p;
    };
    int*   flags   = (int*)alloc(512);
    float* dis     = (float*)alloc((size_t)(N_NODES + 64) * 4);
    int*   deg     = (int*)alloc((size_t)N_NODES * 4);
    int*   row     = (int*)alloc((size_t)(N_NODES + 1) * 4);
    int*   bsums   = (int*)alloc(128 * 4);
    int*   gcur    = (int*)alloc((size_t)NBUK * 4);
    int*   fifo    = (int*)alloc((size_t)NBUK * BUK_CAP * 4);   // 9.4 MB
    int*   csr_src = (int*)alloc((size_t)N_EDGES * 4);
    __half* t0s = (__half*)alloc((size_t)4 * T0SL4 * 2);
    __half* h   = (__half*)alloc((size_t)(N_NODES + 32) * HID * 2);
    float* out_acc = (float*)alloc((size_t)N_NODES * OUT_DIM * 4);
    float* bsf     = (float*)alloc((size_t)LAYERS * HID * 4);
    unsigned short* wpack = (unsigned short*)alloc((size_t)61440 * 2);

    const int nblkN  = (N_NODES + 255) / 256;
    const int nblkS1 = (N_EDGES + S1_EPB - 1) / S1_EPB;   // 782
    const int nblkMM = (N_NODES + 63) / 64;               // 1563
    const int nblkAG = ((N_NODES + AGG_N - 1) / AGG_N) * 4;  // 782*4 = 3128

    detect_kernel<<<1, 64, 0, stream>>>(x, ei, flags, gcur);
    pack_params_kernel<<<80, 256, 0, stream>>>(bs, lin_w, W0, Ws, flags, bsf, wpack);
    bucket1_kernel<<<nblkS1, 256, 0, stream>>>(ei, flags, gcur, fifo);
    deg_fifo_kernel<<<NBUK, 256, 0, stream>>>(gcur, fifo, deg, dis);
    scan1_kernel<<<SCAN_NB, 256, 0, stream>>>(deg, row, bsums);
    scan2_kernel<<<1, 128, 0, stream>>>(bsums);
    scan3_kernel<<<nblkN, 256, 0, stream>>>(row, bsums);
    bucket2_kernel<<<NBUK, 256, 0, stream>>>(gcur, fifo, row, csr_src);

    const unsigned short* wJ0 = wpack + 36864;
    for (int l = 0; l < LAYERS; l++) {
        if (l == 0) {
            mm_mfma_kernel<4, 0, true><<<nblkMM, 256, 0, stream>>>(
                x, x, flags, wpack, nullptr, dis, t0s, nullptr);
        } else if (l == 1) {
            mm_mfma_kernel<2, 1, false><<<nblkMM, 256, 0, stream>>>(
                h, h, flags, wpack + 8192, wJ0, dis, t0s, out_acc);
        } else {
            mm_mfma_kernel<2, 2, false><<<nblkMM, 256, 0, stream>>>(
                h, h, flags, wpack + 8192 + (size_t)(l - 1) * 4096,
                wJ0 + (size_t)(l - 1) * 3072, dis, t0s, out_acc);
        }
        agg_kernel<<<nblkAG, 256, 0, stream>>>(t0s, row, csr_src,
                                               bsf + (size_t)l * HID, h);
    }
    jk_final_kernel<<<nblkMM, 256, 0, stream>>>(h, wJ0 + (size_t)7 * 3072, out_acc,
                                                lin_b, flags, d_out);
}

// Round 6
// 626.981 us; speedup vs baseline: 1.1426x; 1.0019x over previous
//
#include <hip/hip_runtime.h>
#include <hip/hip_bf16.h>
#include <hip/hip_fp16.h>

#define N_NODES 100000
#define N_EDGES 1600000
#define HID     64
#define LAYERS  8
#define OUT_DIM 40
#define SCAN_NB 98   // ceil(100000/1024)
#define T0SL4   ((size_t)(N_NODES + 32) * 16)   // elements per t0 quarter-slice (16 feats)
#define ZROW    N_NODES  // guaranteed-zero row in each slice (mm writes 0 to rows >= N_NODES)
#define NBUK    196      // ceil(100000/512) buckets of 512 nodes
#define BUK_CAP 12000    // avg 8163/bucket -> huge sigma headroom
#define S1_EPB  2048     // edges per bucket1 block (256 thr x 8)
#define AGG_N   128      // nodes per agg block
#define AGG_CAP 3072     // staged csr entries (mean 2048, +22 sigma), 12KB LDS

typedef __attribute__((ext_vector_type(8))) short short8;
typedef __attribute__((ext_vector_type(8))) _Float16 half8;
typedef __attribute__((ext_vector_type(4))) float float4v;

// ---------- runtime environment hedges ----------
// flags[0] = 1 if feature inputs are float32 (else bf16)
// flags[1] = 1 if edge_index is int64 (else int32)
__device__ inline float ldext(const void* p, bool f32, size_t i) {
    return f32 ? ((const float*)p)[i]
               : __bfloat162float(((const __hip_bfloat16*)p)[i]);
}
__device__ inline int load_edge(const void* raw, bool is64, long long idx) {
    return is64 ? (int)((const long long*)raw)[idx] : ((const int*)raw)[idx];
}
__device__ inline unsigned pack_bf16x2(float lo, float hi) {
    union { __hip_bfloat16 b; unsigned short u; } a, b;
    a.b = __float2bfloat16(lo);
    b.b = __float2bfloat16(hi);
    return ((unsigned)b.u << 16) | a.u;
}
__device__ inline unsigned short bf16bits(float v) {
    union { __hip_bfloat16 b; unsigned short u; } a;
    a.b = __float2bfloat16(v);
    return a.u;
}
__device__ inline unsigned short f16bits(float v) {
    union { __half h; unsigned short u; } a;
    a.h = __float2half_rn(v);
    return a.u;
}
__device__ inline __half2 u2h2(unsigned u) {
    union { unsigned u; __half2 h; } x; x.u = u; return x.h;
}
__device__ inline unsigned h22u(__half2 h) {
    union { unsigned u; __half2 h; } x; x.h = h; return x.u;
}

// DPP lane-rotation move (VALU pipe; replaces ds-pipe shuffles in the ep-reduce).
// 0x4E = quad_perm[2,3,0,1] (xor 2); 0x124 = row_ror:4; 0x128 = row_ror:8.
// Rotations within a row of 16 are valid for a commutative sum over lane bits 1..3
// and preserve bit 0 (fp parity).
template <int CTRL>
__device__ inline unsigned dppu(unsigned v) {
    return (unsigned)__builtin_amdgcn_update_dpp((int)v, (int)v, CTRL, 0xF, 0xF, false);
}

// also zeroes gcur (fused former zero_int_kernel)
__global__ void detect_kernel(const void* x, const void* ei, int* flags, int* gcur) {
    int t = threadIdx.x;  // 64 threads
    for (int i = t; i < NBUK; i += 64) gcur[i] = 0;
    float v = fabsf(__bfloat162float(((const __hip_bfloat16*)x)[t]));
    bool inband = (v >= 0.00390625f && v <= 16.0f);
    unsigned long long m = __ballot(inband);
    if (t == 0) {
        flags[0] = (__popcll(m) < 48) ? 1 : 0;  // fp32 misread as bf16 -> ~33/64 in band
        const int* e32 = (const int*)ei;
        flags[1] = ((e32[1] | e32[3] | e32[5] | e32[7]) == 0) ? 1 : 0;
    }
}

// pack: bias (fp32); W0 as bf16 MFMA B-frags; W1..7 and lwB as f16 MFMA B-frags.
__global__ __launch_bounds__(256) void pack_params_kernel(const void* bs, const void* lin_w,
                                                          const void* W0, const void* Ws,
                                                          const int* __restrict__ flags,
                                                          float* __restrict__ bsf,
                                                          unsigned short* __restrict__ wpack) {
    bool f32 = flags[0] != 0;
    int gid = blockIdx.x * 256 + threadIdx.x;
    int stride = gridDim.x * 256;
    for (int idx = gid; idx < LAYERS * HID; idx += stride) bsf[idx] = ldext(bs, f32, idx);
    // layer 0 W: K=128 (KS=4), 8192 elements, bf16 (A = x is bf16)
    for (int idx = gid; idx < 8192; idx += stride) {
        int j = idx & 7, lane = (idx >> 3) & 63, rest = idx >> 9;
        int ks = rest & 3, ct = rest >> 2;
        int quad = lane >> 4, m = lane & 15;
        wpack[idx] = bf16bits(ldext(W0, f32, (size_t)(ks * 32 + quad * 8 + j) * 64 + ct * 16 + m));
    }
    // layers 1..7 W: K=64 (KS=2), 4096 each, f16 (A = h is f16)
    for (int idx = gid; idx < 7 * 4096; idx += stride) {
        int l = idx >> 12, r = idx & 4095;
        int j = r & 7, lane = (r >> 3) & 63, rest = r >> 9;
        int ks = rest & 1, ct = rest >> 1;
        int quad = lane >> 4, m = lane & 15;
        wpack[8192 + idx] = f16bits(
            ldext(Ws, f32, (size_t)l * 4096 + (size_t)(ks * 32 + quad * 8 + j) * 64 + ct * 16 + m));
    }
    // lwB: 8 layers x 3072 (3 ct x 2 ks x 64 lanes x 8), f16
    for (int idx = gid; idx < LAYERS * 3072; idx += stride) {
        int l = idx / 3072, r = idx % 3072;
        int j = r & 7, lane = (r >> 3) & 63, rest = r >> 9;
        int ks = rest & 1, ct = rest >> 1;
        int quad = lane >> 4, m = lane & 15;
        int col = ct * 16 + m;
        int k = l * 64 + ks * 32 + quad * 8 + j;
        wpack[36864 + idx] = (col < OUT_DIM)
            ? f16bits(ldext(lin_w, f32, (size_t)k * OUT_DIM + col)) : (unsigned short)0;
    }
}

// ---------- phase 1: LDS counting-sort append into per-bucket FIFOs ----------
__global__ __launch_bounds__(256) void bucket1_kernel(const void* ei_raw, const int* __restrict__ flags,
                                                      int* __restrict__ gcur, int* __restrict__ fifo) {
    __shared__ int lhist[NBUK];
    __shared__ int lbase[NBUK];
    bool is64 = flags[1] != 0;
    int t = threadIdx.x;
    for (int i = t; i < NBUK; i += 256) lhist[i] = 0;
    __syncthreads();
    int e0 = blockIdx.x * S1_EPB;
    int rec[8], bk[8], loff[8];
#pragma unroll
    for (int j = 0; j < 8; j++) {
        int e = e0 + j * 256 + t;
        bk[j] = -1;
        if (e < N_EDGES) {
            int s = load_edge(ei_raw, is64, e);
            int d = load_edge(ei_raw, is64, (long long)N_EDGES + e);
            int b = d >> 9;
            bk[j] = b;
            rec[j] = ((d & 511) << 17) | s;
            loff[j] = atomicAdd(&lhist[b], 1);
        }
    }
    __syncthreads();
    for (int i = t; i < NBUK; i += 256)
        lbase[i] = (lhist[i] > 0) ? atomicAdd(&gcur[i], lhist[i]) : 0;
    __syncthreads();
#pragma unroll
    for (int j = 0; j < 8; j++) {
        if (bk[j] >= 0) {
            int idx = lbase[bk[j]] + loff[j];
            if (idx < BUK_CAP) fifo[bk[j] * BUK_CAP + idx] = rec[j];
        }
    }
}

// ---------- degree + dis from FIFO (LDS counters; fused former calc_dis) ----------
__global__ __launch_bounds__(256) void deg_fifo_kernel(const int* __restrict__ gcur,
                                                       const int* __restrict__ fifo,
                                                       int* __restrict__ deg,
                                                       float* __restrict__ dis) {
    __shared__ int ldeg[512];
    int b = blockIdx.x, t = threadIdx.x;
    ldeg[t] = 0;
    ldeg[t + 256] = 0;
    __syncthreads();
    int cnt = min(gcur[b], BUK_CAP);
    for (int i = t; i < cnt; i += 256)
        atomicAdd(&ldeg[fifo[b * BUK_CAP + i] >> 17], 1);
    __syncthreads();
    int n0 = b * 512 + t;
    if (n0 < N_NODES) {
        int d = ldeg[t];
        deg[n0] = d;
        dis[n0] = rsqrtf((float)(d + 1));  // +1 self-loop
    }
    if (n0 + 256 < N_NODES) {
        int d = ldeg[t + 256];
        deg[n0 + 256] = d;
        dis[n0 + 256] = rsqrtf((float)(d + 1));
    }
}

// exclusive scan of deg -> row (3-kernel, 1024 elems/block)
__global__ __launch_bounds__(256) void scan1_kernel(const int* __restrict__ deg, int* __restrict__ row,
                                                    int* __restrict__ bsums) {
    __shared__ int sd[256];
    int t = threadIdx.x;
    int base = blockIdx.x * 1024 + t * 4;
    int v[4];
#pragma unroll
    for (int j = 0; j < 4; j++) {
        int idx = base + j;
        v[j] = (idx < N_NODES) ? deg[idx] : 0;
    }
    int s4 = v[0] + v[1] + v[2] + v[3];
    sd[t] = s4;
    __syncthreads();
    for (int off = 1; off < 256; off <<= 1) {
        int x = (t >= off) ? sd[t - off] : 0;
        __syncthreads();
        sd[t] += x;
        __syncthreads();
    }
    int run = sd[t] - s4;  // exclusive
#pragma unroll
    for (int j = 0; j < 4; j++) {
        int idx = base + j;
        if (idx < N_NODES) row[idx] = run;
        run += v[j];
    }
    if (t == 255) bsums[blockIdx.x] = sd[255];
}

__global__ void scan2_kernel(int* bsums) {
    __shared__ int sd[128];
    int t = threadIdx.x;
    int v = (t < SCAN_NB) ? bsums[t] : 0;
    sd[t] = v;
    __syncthreads();
    for (int off = 1; off < 128; off <<= 1) {
        int x = (t >= off) ? sd[t - off] : 0;
        __syncthreads();
        sd[t] += x;
        __syncthreads();
    }
    if (t < SCAN_NB) bsums[t] = sd[t] - v;  // exclusive block offsets
}

__global__ __launch_bounds__(256) void scan3_kernel(int* __restrict__ row, const int* __restrict__ bsums) {
    int i = blockIdx.x * 256 + threadIdx.x;
    if (i < N_NODES) row[i] += bsums[i >> 10];
    if (i == 0) row[N_NODES] = N_EDGES;
}

// ---------- phase 2: per-bucket scatter to final CSR with LDS cursors ----------
__global__ __launch_bounds__(256) void bucket2_kernel(const int* __restrict__ gcur,
                                                      const int* __restrict__ fifo,
                                                      const int* __restrict__ row,
                                                      int* __restrict__ csr_src) {
    __shared__ int lcur[512];
    int b = blockIdx.x, t = threadIdx.x;
    int n0 = b * 512 + t;
    lcur[t] = row[min(n0, N_NODES)];
    lcur[t + 256] = row[min(n0 + 256, N_NODES)];
    __syncthreads();
    int cnt = min(gcur[b], BUK_CAP);
    for (int i = t; i < cnt; i += 256) {
        int r = fifo[b * BUK_CAP + i];
        int pos = atomicAdd(&lcur[r >> 17], 1);
        csr_src[pos] = r & 0x1FFFF;
    }
}

// ---------- MFMA matmul: t0s (f16, 4 quarter-slices, dis-prescaled) = dis .* (h @ W) ----------
// ABF16: A/wW are bf16 (layer 0, A = x, converted in-register if fp32); else f16 (A = h).
// JK: 0 = none, 1 = out_acc = h @ lwB, 2 = out_acc += h @ lwB (exclusive per node)
// R6 FIX: rows >= N_NODES (pad rows incl. ZROW) are written as ZERO each layer,
// making agg's zero-row gather routing sound (R5 bug: pad rows held garbage).
template <int KS, int JK, bool ABF16>
__global__ __launch_bounds__(256) void mm_mfma_kernel(const void* __restrict__ h0,
                                                      const void* __restrict__ h1,
                                                      const int* __restrict__ flags,
                                                      const unsigned short* __restrict__ wW,
                                                      const unsigned short* __restrict__ wJ,
                                                      const float* __restrict__ dis,
                                                      __half* __restrict__ t0s,
                                                      float* __restrict__ out_acc) {
    constexpr int K = KS * 32;
    int wave = threadIdx.x >> 6, lane = threadIdx.x & 63;
    int quad = lane >> 4, m = lane & 15;
    int nb = blockIdx.x * 64 + wave * 16;
    int ra = nb + m;
    if (ra > N_NODES - 1) ra = N_NODES - 1;  // clamp tail (avoids OOB read)
    short8 a[KS];
    if constexpr (ABF16) {
        if (flags[0]) {
            // fp32 input: load floats, convert to bf16 in-register (replaces convert_x pass)
            const float* xr = (const float*)h1 + (size_t)ra * K + quad * 8;
#pragma unroll
            for (int ks = 0; ks < KS; ks++) {
                float4 f0 = *(const float4*)(xr + ks * 32);
                float4 f1 = *(const float4*)(xr + ks * 32 + 4);
                short8 v;
                v[0] = (short)bf16bits(f0.x); v[1] = (short)bf16bits(f0.y);
                v[2] = (short)bf16bits(f0.z); v[3] = (short)bf16bits(f0.w);
                v[4] = (short)bf16bits(f1.x); v[5] = (short)bf16bits(f1.y);
                v[6] = (short)bf16bits(f1.z); v[7] = (short)bf16bits(f1.w);
                a[ks] = v;
            }
        } else {
            const short* hrow = (const short*)h0 + (size_t)ra * K + quad * 8;
#pragma unroll
            for (int ks = 0; ks < KS; ks++) a[ks] = *(const short8*)(hrow + ks * 32);
        }
    } else {
        const short* hrow = (const short*)h0 + (size_t)ra * K + quad * 8;
#pragma unroll
        for (int ks = 0; ks < KS; ks++) a[ks] = *(const short8*)(hrow + ks * 32);
    }
    float dr[4];
#pragma unroll
    for (int r = 0; r < 4; r++) {
        int rw = nb + quad * 4 + r;
        dr[r] = (rw < N_NODES) ? dis[rw] : 0.f;  // pad rows -> write exact zero
    }
#pragma unroll
    for (int ct = 0; ct < 4; ct++) {
        float4v acc = (float4v){0.f, 0.f, 0.f, 0.f};
#pragma unroll
        for (int ks = 0; ks < KS; ks++) {
            short8 b = *(const short8*)(wW + ((ct * KS + ks) * 64 + lane) * 8);
            if constexpr (ABF16)
                acc = __builtin_amdgcn_mfma_f32_16x16x32_bf16(a[ks], b, acc, 0, 0, 0);
            else
                acc = __builtin_amdgcn_mfma_f32_16x16x32_f16(
                    __builtin_bit_cast(half8, a[ks]), __builtin_bit_cast(half8, b), acc, 0, 0, 0);
        }
        // quarter-slice ct holds features ct*16..ct*16+15
#pragma unroll
        for (int r = 0; r < 4; r++) {
            t0s[(size_t)ct * T0SL4 + (size_t)(nb + quad * 4 + r) * 16 + m] =
                __float2half(acc[r] * dr[r]);
        }
    }
    if (JK) {
#pragma unroll
        for (int ct = 0; ct < 3; ct++) {
            float4v j = (float4v){0.f, 0.f, 0.f, 0.f};
#pragma unroll
            for (int ks = 0; ks < KS; ks++) {
                short8 b = *(const short8*)(wJ + ((ct * KS + ks) * 64 + lane) * 8);
                if constexpr (ABF16)
                    j = __builtin_amdgcn_mfma_f32_16x16x32_bf16(a[ks], b, j, 0, 0, 0);
                else
                    j = __builtin_amdgcn_mfma_f32_16x16x32_f16(
                        __builtin_bit_cast(half8, a[ks]), __builtin_bit_cast(half8, b), j, 0, 0, 0);
            }
            int col = ct * 16 + m;
            if (col < OUT_DIM) {
#pragma unroll
                for (int r = 0; r < 4; r++) {
                    int rw = nb + quad * 4 + r;
                    if (rw < N_NODES) {
                        size_t o = (size_t)rw * OUT_DIM + col;
                        if (JK == 1) out_acc[o] = j[r];
                        else out_acc[o] += j[r];
                    }
                }
            }
        }
    }
}

// ---------- aggregation: 4 XCD-affine quarter-slices, staged csr, 4 nodes/wave ----------
// R6 (= R5 with sound zero-row):
//  * sched_barrier(0) after each ISSUE pins the gathers at their issue point —
//    R2/R4 showed the scheduler sinks them to the consume (VGPR 32/36 = collapsed
//    pipeline); the fence forces the 3-deep pipeline to stay live at ISA level;
//  * masked gathers routed to ZROW (row N_NODES), which mm now zeroes each layer:
//    consume is a pure hadd2 tree, no mask registers;
//  * self-loop merged into round 0; DPP ep-reduce; deg>23 tail behind __any.
__global__ __launch_bounds__(256, 6) void agg_kernel(const __half* __restrict__ t0s,
                                                     const int* __restrict__ row,
                                                     const int* __restrict__ csr_src,
                                                     const float* __restrict__ bsf,   // this layer, 64 f32
                                                     __half* __restrict__ h) {
    __shared__ int lrow[AGG_N + 1];
    __shared__ __align__(16) int lcsr[AGG_CAP + 32];
    int t = threadIdx.x;
    int s = blockIdx.x & 3;
    int nb = (blockIdx.x >> 2) * AGG_N;
    const __half* tsl = t0s + (size_t)s * T0SL4;

    for (int i = t; i <= AGG_N; i += 256) {
        int n = nb + i;
        lrow[i] = row[n > N_NODES ? N_NODES : n];
    }
    __syncthreads();
    int rs0 = lrow[0];
    int cnt_raw = lrow[AGG_N] - rs0;
    int cnt = min(cnt_raw, AGG_CAP);

    int wave = t >> 6, lane = t & 63;
    // async staging into lcsr[4..4+cnt): wave-uniform LDS base + lane*16 dest,
    // per-lane global src; chunks of 256 entries (1KB/wave-instr).
    for (int c = wave; c * 256 < cnt; c += 4) {
        const int* gsrc = csr_src + rs0 + c * 256 + lane * 4;
        __builtin_amdgcn_global_load_lds(
            (const __attribute__((address_space(1))) unsigned int*)gsrc,
            (__attribute__((address_space(3))) unsigned int*)&lcsr[4 + c * 256],
            16, 0, 0);
    }
    asm volatile("s_waitcnt vmcnt(0)" ::: "memory");
    __syncthreads();

    int ns = lane >> 4, ep = (lane >> 1) & 7, fp = lane & 1;
    const __half2 h2zero = __floats2half2_rn(0.f, 0.f);

    if (cnt_raw <= AGG_CAP) {
        uint4 Av0, Av1, Av2; int Ars, Are;
        uint4 Bv0, Bv1, Bv2; int Brs, Bre;
        uint4 Cv0, Cv1, Cv2; int Crs, Cre;

#define AGG_ISSUE(P, v0, v1, v2, rs_, re_)                                      \
        do {                                                                    \
            int nl_ = (P) * 16 + wave * 4 + ns;                                 \
            int node_ = nb + nl_;                                               \
            bool valid_ = node_ < N_NODES;                                      \
            rs_ = valid_ ? lrow[nl_] : 0;                                       \
            re_ = valid_ ? lrow[nl_ + 1] : 0;                                   \
            int b_ = max(rs_ - rs0, 0) + ep;                                    \
            int se0_ = lcsr[b_ + 3];   /* edge rs+ep-1 */                       \
            int se1_ = lcsr[b_ + 11];  /* edge rs+ep+7 */                       \
            int se2_ = lcsr[b_ + 19];  /* edge rs+ep+15 */                      \
            se0_ = (ep == 0) ? (valid_ ? node_ : ZROW)                          \
                             : ((rs_ + ep - 1 < re_) ? se0_ : ZROW);            \
            se1_ = (rs_ + ep + 7  < re_) ? se1_ : ZROW;                         \
            se2_ = (rs_ + ep + 15 < re_) ? se2_ : ZROW;                         \
            v0 = *(const uint4*)(tsl + (size_t)se0_ * 16 + fp * 8);             \
            v1 = *(const uint4*)(tsl + (size_t)se1_ * 16 + fp * 8);             \
            v2 = *(const uint4*)(tsl + (size_t)se2_ * 16 + fp * 8);             \
        } while (0)

#define AGG_CONSUME(P, v0, v1, v2, rs_, re_)                                    \
        do {                                                                    \
            int nl_ = (P) * 16 + wave * 4 + ns;                                 \
            int node_ = nb + nl_;                                               \
            bool valid_ = node_ < N_NODES;                                      \
            __half2 a0_ = __hadd2(__hadd2(u2h2(v0.x), u2h2(v1.x)), u2h2(v2.x)); \
            __half2 a1_ = __hadd2(__hadd2(u2h2(v0.y), u2h2(v1.y)), u2h2(v2.y)); \
            __half2 a2_ = __hadd2(__hadd2(u2h2(v0.z), u2h2(v1.z)), u2h2(v2.z)); \
            __half2 a3_ = __hadd2(__hadd2(u2h2(v0.w), u2h2(v1.w)), u2h2(v2.w)); \
            if (__builtin_expect(__any(re_ - rs_ > 23), 0)) {                   \
                for (int q_ = rs_ + 23 + ep; q_ < re_; q_ += 8) {               \
                    int se_ = lcsr[4 + q_ - rs0];                               \
                    uint4 v_ = *(const uint4*)(tsl + (size_t)se_ * 16 + fp * 8);\
                    a0_ = __hadd2(a0_, u2h2(v_.x));                             \
                    a1_ = __hadd2(a1_, u2h2(v_.y));                             \
                    a2_ = __hadd2(a2_, u2h2(v_.z));                             \
                    a3_ = __hadd2(a3_, u2h2(v_.w));                             \
                }                                                               \
            }                                                                   \
            a0_ = __hadd2(a0_, u2h2(dppu<0x4E>(h22u(a0_))));                    \
            a1_ = __hadd2(a1_, u2h2(dppu<0x4E>(h22u(a1_))));                    \
            a2_ = __hadd2(a2_, u2h2(dppu<0x4E>(h22u(a2_))));                    \
            a3_ = __hadd2(a3_, u2h2(dppu<0x4E>(h22u(a3_))));                    \
            a0_ = __hadd2(a0_, u2h2(dppu<0x124>(h22u(a0_))));                   \
            a1_ = __hadd2(a1_, u2h2(dppu<0x124>(h22u(a1_))));                   \
            a2_ = __hadd2(a2_, u2h2(dppu<0x124>(h22u(a2_))));                   \
            a3_ = __hadd2(a3_, u2h2(dppu<0x124>(h22u(a3_))));                   \
            a0_ = __hadd2(a0_, u2h2(dppu<0x128>(h22u(a0_))));                   \
            a1_ = __hadd2(a1_, u2h2(dppu<0x128>(h22u(a1_))));                   \
            a2_ = __hadd2(a2_, u2h2(dppu<0x128>(h22u(a2_))));                   \
            a3_ = __hadd2(a3_, u2h2(dppu<0x128>(h22u(a3_))));                   \
            if (valid_ && ep == 0) {                                            \
                float di_ = rsqrtf((float)(re_ - rs_ + 1));                     \
                const float* bb_ = bsf + s * 16 + fp * 8;                       \
                float f_[8];                                                    \
                f_[0] = __low2float(a0_); f_[1] = __high2float(a0_);            \
                f_[2] = __low2float(a1_); f_[3] = __high2float(a1_);            \
                f_[4] = __low2float(a2_); f_[5] = __high2float(a2_);            \
                f_[6] = __low2float(a3_); f_[7] = __high2float(a3_);            \
                _Pragma("unroll")                                               \
                for (int j_ = 0; j_ < 8; j_++)                                  \
                    f_[j_] = fmaxf(di_ * f_[j_] + bb_[j_], 0.f);                \
                uint4 pv_;                                                      \
                pv_.x = h22u(__floats2half2_rn(f_[0], f_[1]));                  \
                pv_.y = h22u(__floats2half2_rn(f_[2], f_[3]));                  \
                pv_.z = h22u(__floats2half2_rn(f_[4], f_[5]));                  \
                pv_.w = h22u(__floats2half2_rn(f_[6], f_[7]));                  \
                *(uint4*)(h + (size_t)node_ * 64 + s * 16 + fp * 8) = pv_;      \
            }                                                                   \
        } while (0)

#define SBAR __builtin_amdgcn_sched_barrier(0)

        AGG_ISSUE(0, Av0, Av1, Av2, Ars, Are); SBAR;
        AGG_ISSUE(1, Bv0, Bv1, Bv2, Brs, Bre); SBAR;
        AGG_ISSUE(2, Cv0, Cv1, Cv2, Crs, Cre); SBAR;
        AGG_CONSUME(0, Av0, Av1, Av2, Ars, Are);
        AGG_ISSUE(3, Av0, Av1, Av2, Ars, Are); SBAR;
        AGG_CONSUME(1, Bv0, Bv1, Bv2, Brs, Bre);
        AGG_ISSUE(4, Bv0, Bv1, Bv2, Brs, Bre); SBAR;
        AGG_CONSUME(2, Cv0, Cv1, Cv2, Crs, Cre);
        AGG_ISSUE(5, Cv0, Cv1, Cv2, Crs, Cre); SBAR;
        AGG_CONSUME(3, Av0, Av1, Av2, Ars, Are);
        AGG_ISSUE(6, Av0, Av1, Av2, Ars, Are); SBAR;
        AGG_CONSUME(4, Bv0, Bv1, Bv2, Brs, Bre);
        AGG_ISSUE(7, Bv0, Bv1, Bv2, Brs, Bre); SBAR;
        AGG_CONSUME(5, Cv0, Cv1, Cv2, Crs, Cre);
        AGG_CONSUME(6, Av0, Av1, Av2, Ars, Are);
        AGG_CONSUME(7, Bv0, Bv1, Bv2, Brs, Bre);
#undef SBAR
#undef AGG_ISSUE
#undef AGG_CONSUME
    } else {
        // slow path: staged-LDS overflow (block-uniform, essentially never taken)
#pragma unroll
        for (int pass = 0; pass < AGG_N / 16; pass++) {
            int nl = pass * 16 + wave * 4 + ns;
            int node = nb + nl;
            bool valid = node < N_NODES;
            int rs = valid ? lrow[nl] : 0;
            int re = valid ? lrow[nl + 1] : 0;
            __half2 a2[4];
#pragma unroll
            for (int r = 0; r < 4; r++) a2[r] = h2zero;
            if (valid && ep == 0) {
                uint4 v = *(const uint4*)(tsl + (size_t)node * 16 + fp * 8);
                a2[0] = __hadd2(a2[0], u2h2(v.x));
                a2[1] = __hadd2(a2[1], u2h2(v.y));
                a2[2] = __hadd2(a2[2], u2h2(v.z));
                a2[3] = __hadd2(a2[3], u2h2(v.w));
            }
            for (int base = rs; base + ep < re; base += 8) {
                int idx = base + ep - rs0;
                int se = (idx < AGG_CAP) ? lcsr[4 + idx] : csr_src[base + ep];
                uint4 v = *(const uint4*)(tsl + (size_t)se * 16 + fp * 8);
                a2[0] = __hadd2(a2[0], u2h2(v.x));
                a2[1] = __hadd2(a2[1], u2h2(v.y));
                a2[2] = __hadd2(a2[2], u2h2(v.z));
                a2[3] = __hadd2(a2[3], u2h2(v.w));
            }
#pragma unroll
            for (int st = 2; st <= 8; st <<= 1) {
#pragma unroll
                for (int r = 0; r < 4; r++)
                    a2[r] = __hadd2(a2[r], u2h2(__shfl_xor(h22u(a2[r]), st)));
            }
            if (valid && ep == 0) {
                float di = rsqrtf((float)(re - rs + 1));
                const float* bb = bsf + s * 16 + fp * 8;
                float a[8];
#pragma unroll
                for (int r = 0; r < 4; r++) {
                    a[2 * r]     = __low2float(a2[r]);
                    a[2 * r + 1] = __high2float(a2[r]);
                }
#pragma unroll
                for (int j = 0; j < 8; j++) a[j] = fmaxf(di * a[j] + bb[j], 0.f);
                uint4 pv;
                pv.x = h22u(__floats2half2_rn(a[0], a[1]));
                pv.y = h22u(__floats2half2_rn(a[2], a[3]));
                pv.z = h22u(__floats2half2_rn(a[4], a[5]));
                pv.w = h22u(__floats2half2_rn(a[6], a[7]));
                *(uint4*)(h + (size_t)node * 64 + s * 16 + fp * 8) = pv;
            }
        }
    }
}

// ---------- final: out = out_acc + h7 @ lwB7 + lin_b ----------
__global__ __launch_bounds__(256) void jk_final_kernel(const __half* __restrict__ h,
                                                       const unsigned short* __restrict__ wJ,
                                                       const float* __restrict__ out_acc,
                                                       const void* __restrict__ lin_b,
                                                       const int* __restrict__ flags,
                                                       void* __restrict__ d_out) {
    bool f32 = flags[0] != 0;
    int wave = threadIdx.x >> 6, lane = threadIdx.x & 63;
    int quad = lane >> 4, m = lane & 15;
    int nb = blockIdx.x * 64 + wave * 16;
    int ra = nb + m;
    if (ra > N_NODES - 1) ra = N_NODES - 1;
    const short* hrow = (const short*)(h + (size_t)ra * 64) + quad * 8;
    short8 a0 = *(const short8*)(hrow);
    short8 a1 = *(const short8*)(hrow + 32);
#pragma unroll
    for (int ct = 0; ct < 3; ct++) {
        float4v j = (float4v){0.f, 0.f, 0.f, 0.f};
        short8 b0 = *(const short8*)(wJ + ((ct * 2 + 0) * 64 + lane) * 8);
        short8 b1 = *(const short8*)(wJ + ((ct * 2 + 1) * 64 + lane) * 8);
        j = __builtin_amdgcn_mfma_f32_16x16x32_f16(
            __builtin_bit_cast(half8, a0), __builtin_bit_cast(half8, b0), j, 0, 0, 0);
        j = __builtin_amdgcn_mfma_f32_16x16x32_f16(
            __builtin_bit_cast(half8, a1), __builtin_bit_cast(half8, b1), j, 0, 0, 0);
        int col = ct * 16 + m;
        if (col < OUT_DIM) {
            float lb = ldext(lin_b, f32, col);
#pragma unroll
            for (int r = 0; r < 4; r++) {
                int rw = nb + quad * 4 + r;
                if (rw < N_NODES) {
                    float v = out_acc[(size_t)rw * OUT_DIM + col] + j[r] + lb;
                    if (f32) ((float*)d_out)[(size_t)rw * OUT_DIM + col] = v;
                    else ((__hip_bfloat16*)d_out)[(size_t)rw * OUT_DIM + col] = __float2bfloat16(v);
                }
            }
        }
    }
}

extern "C" void kernel_launch(void* const* d_in, const int* in_sizes, int n_in,
                              void* d_out, int out_size, void* d_ws, size_t ws_size,
                              hipStream_t stream) {
    const void* x     = d_in[0];
    const void* W0    = d_in[1];
    const void* Ws    = d_in[2];
    const void* bs    = d_in[3];
    const void* lin_w = d_in[4];
    const void* lin_b = d_in[5];
    const void* ei    = d_in[6];

    size_t off = 0;
    auto alloc = [&](size_t bytes) -> void* {
        void* p = (char*)d_ws + off;
        off += (bytes + 511) & ~(size_t)511;
        return p;
    };
    int*   flags   = (int*)alloc(512);
    float* dis     = (float*)alloc((size_t)(N_NODES + 64) * 4);
    int*   deg     = (int*)alloc((size_t)N_NODES * 4);
    int*   row     = (int*)alloc((size_t)(N_NODES + 1) * 4);
    int*   bsums   = (int*)alloc(128 * 4);
    int*   gcur    = (int*)alloc((size_t)NBUK * 4);
    int*   fifo    = (int*)alloc((size_t)NBUK * BUK_CAP * 4);   // 9.4 MB
    int*   csr_src = (int*)alloc((size_t)N_EDGES * 4);
    __half* t0s = (__half*)alloc((size_t)4 * T0SL4 * 2);
    __half* h   = (__half*)alloc((size_t)(N_NODES + 32) * HID * 2);
    float* out_acc = (float*)alloc((size_t)N_NODES * OUT_DIM * 4);
    float* bsf     = (float*)alloc((size_t)LAYERS * HID * 4);
    unsigned short* wpack = (unsigned short*)alloc((size_t)61440 * 2);

    const int nblkN  = (N_NODES + 255) / 256;
    const int nblkS1 = (N_EDGES + S1_EPB - 1) / S1_EPB;   // 782
    const int nblkMM = (N_NODES + 63) / 64;               // 1563
    const int nblkAG = ((N_NODES + AGG_N - 1) / AGG_N) * 4;  // 782*4 = 3128

    detect_kernel<<<1, 64, 0, stream>>>(x, ei, flags, gcur);
    pack_params_kernel<<<80, 256, 0, stream>>>(bs, lin_w, W0, Ws, flags, bsf, wpack);
    bucket1_kernel<<<nblkS1, 256, 0, stream>>>(ei, flags, gcur, fifo);
    deg_fifo_kernel<<<NBUK, 256, 0, stream>>>(gcur, fifo, deg, dis);
    scan1_kernel<<<SCAN_NB, 256, 0, stream>>>(deg, row, bsums);
    scan2_kernel<<<1, 128, 0, stream>>>(bsums);
    scan3_kernel<<<nblkN, 256, 0, stream>>>(row, bsums);
    bucket2_kernel<<<NBUK, 256, 0, stream>>>(gcur, fifo, row, csr_src);

    const unsigned short* wJ0 = wpack + 36864;
    for (int l = 0; l < LAYERS; l++) {
        if (l == 0) {
            mm_mfma_kernel<4, 0, true><<<nblkMM, 256, 0, stream>>>(
                x, x, flags, wpack, nullptr, dis, t0s, nullptr);
        } else if (l == 1) {
            mm_mfma_kernel<2, 1, false><<<nblkMM, 256, 0, stream>>>(
                h, h, flags, wpack + 8192, wJ0, dis, t0s, out_acc);
        } else {
            mm_mfma_kernel<2, 2, false><<<nblkMM, 256, 0, stream>>>(
                h, h, flags, wpack + 8192 + (size_t)(l - 1) * 4096,
                wJ0 + (size_t)(l - 1) * 3072, dis, t0s, out_acc);
        }
        agg_kernel<<<nblkAG, 256, 0, stream>>>(t0s, row, csr_src,
                                               bsf + (size_t)l * HID, h);
    }
    jk_final_kernel<<<nblkMM, 256, 0, stream>>>(h, wJ0 + (size_t)7 * 3072, out_acc,
                                                lin_b, flags, d_out);
}